// Round 1
// 1809.003 us; speedup vs baseline: 1.3926x; 1.3926x over previous
//
#include <hip/hip_runtime.h>
#include <hip/hip_bf16.h>
#include <math.h>

typedef __hip_bfloat16 bf16;
typedef unsigned short ushort;
typedef __bf16 bf16x8 __attribute__((ext_vector_type(8)));
typedef unsigned short u16x8 __attribute__((ext_vector_type(8)));
typedef float f32x4 __attribute__((ext_vector_type(4)));

#define BB 4
#define NN 1024
#define DD 1024
#define HH 16
#define KVH 4
#define HDIM 64
#define SS 128
#define CTXD 2048
#define MLPDIM 4096

__device__ __forceinline__ float bf2f(bf16 v){ return __bfloat162float(v); }
__device__ __forceinline__ bf16 f2bf(float v){ return __float2bfloat16(v); }
__device__ __forceinline__ ushort fbits(float v){ bf16 h = __float2bfloat16(v); return *(ushort*)&h; }
__device__ __forceinline__ float ubf(ushort u){ unsigned int x = ((unsigned int)u) << 16; float f; *(unsigned int*)&f = x; return f; }
__device__ __forceinline__ float sigmf_(float x){ return 1.f/(1.f+expf(-x)); }
__device__ __forceinline__ float geluf_(float x){ return 0.5f*x*(1.f+erff(x*0.70710678118f)); }

// ---------- converts ----------
__global__ void k_copy4(const float4* __restrict__ in, float4* __restrict__ out, int n4){
  int i = blockIdx.x*256 + threadIdx.x;
  if (i < n4) out[i] = in[i];
}
__global__ void k_f2bfv(const float* __restrict__ in, bf16* __restrict__ out, int n){
  int i = blockIdx.x*256 + threadIdx.x;
  if (i < n) out[i] = f2bf(in[i]);
}
__global__ void k_silu(const float* __restrict__ c, float* __restrict__ out, int n){
  int i = blockIdx.x*256 + threadIdx.x;
  if (i < n){ float v = c[i]; out[i] = v*sigmf_(v); }
}
__global__ void k_zero16(unsigned short* __restrict__ p, int n){
  int i = blockIdx.x*256 + threadIdx.x;
  if (i < n) p[i] = 0;
}

// ---------- adaLN: mod = silu(c) @ ada_w + ada_b ----------
__global__ void k_ada(const float* __restrict__ sc, const float* __restrict__ w,
                      const float* __restrict__ b, float* __restrict__ mod){
  int idx = blockIdx.x*256 + threadIdx.x;  // < 4*6144
  int bb = idx / 6144, col = idx % 6144;
  const float* cp = sc + bb*DD;
  float s = 0.f;
  for (int k = 0; k < DD; ++k) s += cp[k]*w[(size_t)k*6144 + col];
  mod[idx] = s + b[col];
}

// ---------- RMSNorm (+optional adaLN scale/shift) ----------
__global__ __launch_bounds__(256) void k_rms(const float* __restrict__ X, const float* __restrict__ w,
                      const float* __restrict__ mod, int sc_off, int sh_off,
                      bf16* __restrict__ out, int use_mod){
  __shared__ float red[256];
  int row = blockIdx.x;
  int b = row >> 10;
  int tid = threadIdx.x;
  const float* xr = X + (size_t)row*DD;
  float s = 0.f;
  #pragma unroll
  for (int i = 0; i < 4; ++i){ float v = xr[tid + i*256]; s += v*v; }
  red[tid] = s; __syncthreads();
  for (int st = 128; st > 0; st >>= 1){ if (tid < st) red[tid] += red[tid+st]; __syncthreads(); }
  float rstd = rsqrtf(red[0]*(1.f/DD) + 1e-6f);
  bf16* orow = out + (size_t)row*DD;
  const float* mrow = use_mod ? (mod + (size_t)b*6*DD) : nullptr;
  #pragma unroll
  for (int i = 0; i < 4; ++i){
    int d = tid + i*256;
    float v = xr[d]*rstd*w[d];
    if (use_mod) v = v*(1.f + mrow[sc_off + d]) + mrow[sh_off + d];
    orow[d] = f2bf(v);
  }
}

// ---------- MFMA GEMM: C(MxN,bf16) = A(MxK,bf16) @ Bw(KxN,fp32) [+bias][gelu] ----------
// M%128==0, N%128==0, K%32==0. Block 256 = 4 waves, each wave 64x64 (4x4 MFMA 16x16x32).
__global__ __launch_bounds__(256,2) void k_mm(const ushort* __restrict__ A, const float* __restrict__ Bw,
                      const float* __restrict__ bias, ushort* __restrict__ C,
                      int M, int N, int K, int act){
  __shared__ ushort As[128*40];   // [m][k] rows padded to 40 (80B, 16B-aligned, 2-way banks)
  __shared__ ushort Bs[32*132];   // [k][n] rows padded to 132 (264B, 2-way banks on frag reads)
  int tid = threadIdx.x, lane = tid & 63, wv = tid >> 6;
  int l15 = lane & 15, quad = lane >> 4;
  int bm = blockIdx.y*128, bn = blockIdx.x*128;
  int wm = (wv & 1)*64, wn = (wv >> 1)*64;
  f32x4 acc[4][4] = {};
  for (int k0 = 0; k0 < K; k0 += 32){
    // stage A: 128x32 bf16, thread loads 2 chunks of 8
    #pragma unroll
    for (int i = 0; i < 2; ++i){
      int c = tid + i*256; int row = c >> 2; int k8 = (c & 3) << 3;
      uint4 v = *(const uint4*)(A + (size_t)(bm+row)*K + k0 + k8);
      *(uint4*)(As + row*40 + k8) = v;
    }
    // stage B: 32x128 fp32 -> bf16, thread loads 4 chunks of 4
    #pragma unroll
    for (int i = 0; i < 4; ++i){
      int c = tid + i*256; int kk = c >> 5; int n4 = (c & 31) << 2;
      float4 v = *(const float4*)(Bw + (size_t)(k0+kk)*N + bn + n4);
      uint2 pk;
      pk.x = (unsigned int)fbits(v.x) | ((unsigned int)fbits(v.y) << 16);
      pk.y = (unsigned int)fbits(v.z) | ((unsigned int)fbits(v.w) << 16);
      *(uint2*)(Bs + kk*132 + n4) = pk;
    }
    __syncthreads();
    bf16x8 af[4], bfr[4];
    #pragma unroll
    for (int mi = 0; mi < 4; ++mi){
      uint4 v = *(const uint4*)(As + (wm + mi*16 + l15)*40 + quad*8);
      af[mi] = __builtin_bit_cast(bf16x8, v);
    }
    #pragma unroll
    for (int nj = 0; nj < 4; ++nj){
      int col = wn + nj*16 + l15;
      u16x8 ev;
      #pragma unroll
      for (int j = 0; j < 8; ++j) ev[j] = Bs[(quad*8 + j)*132 + col];
      bfr[nj] = __builtin_bit_cast(bf16x8, ev);
    }
    #pragma unroll
    for (int mi = 0; mi < 4; ++mi)
      #pragma unroll
      for (int nj = 0; nj < 4; ++nj)
        acc[mi][nj] = __builtin_amdgcn_mfma_f32_16x16x32_bf16(af[mi], bfr[nj], acc[mi][nj], 0, 0, 0);
    __syncthreads();
  }
  // epilogue: C/D layout col=lane&15, row=quad*4+r
  #pragma unroll
  for (int nj = 0; nj < 4; ++nj){
    int col = bn + wn + nj*16 + l15;
    float bv = bias ? bias[col] : 0.f;
    #pragma unroll
    for (int mi = 0; mi < 4; ++mi){
      #pragma unroll
      for (int r = 0; r < 4; ++r){
        int row = bm + wm + mi*16 + quad*4 + r;
        float v = acc[mi][nj][r] + bv;
        if (act) v = geluf_(v);
        C[(size_t)row*N + col] = fbits(v);
      }
    }
  }
}

// ---------- RoPE: in (B,NN,NHp,64) -> out (B,NHp,NN,64), rotated ----------
__global__ void k_rope(const bf16* __restrict__ in, const float* __restrict__ cw,
                       const float* __restrict__ sw, bf16* __restrict__ out, int NHp, int n){
  int idx = blockIdx.x*256 + threadIdx.x;
  if (idx >= n) return;
  int d2 = idx & 31; int t = idx >> 5;
  int nn = t % NN; t /= NN; int h = t % NHp; int b = t / NHp;
  const bf16* base = in + ((size_t)((b*NN+nn)*NHp + h))*HDIM;
  float e = bf2f(base[2*d2]), o = bf2f(base[2*d2+1]);
  float c = cw[nn*32 + d2], s = sw[nn*32 + d2];
  bf16* ob = out + ((size_t)((b*NHp+h)*NN + nn))*HDIM;
  ob[d2]      = f2bf(e*c - o*s);
  ob[32 + d2] = f2bf(e*s + o*c);
}

// ---------- transpose (B,T,NHp,64) -> (B,NHp,T,64) ----------
__global__ void k_tr(const bf16* __restrict__ in, bf16* __restrict__ out, int T, int NHp, int n){
  int idx = blockIdx.x*256 + threadIdx.x;
  if (idx >= n) return;
  int d = idx & 63; int t = idx >> 6;
  int h = t % NHp; t /= NHp; int tok = t % T; int b = t / T;
  out[((size_t)((b*NHp+h)*T + tok))*64 + d] = in[idx];
}

// ---------- V transpose (B,T,NHp,64) -> (B,NHp,64,T) for MFMA PV B-fragments ----------
__global__ void k_trv(const bf16* __restrict__ in, bf16* __restrict__ out, int T, int NHp, int n){
  int idx = blockIdx.x*256 + threadIdx.x;
  if (idx >= n) return;
  int d = idx & 63; int t = idx >> 6;
  int h = t % NHp; t /= NHp; int tok = t % T; int b = t / T;
  out[((size_t)(b*NHp+h)*64 + d)*T + tok] = in[idx];
}

// ---------- MFMA flash attention ----------
// Block = 256 thr = 4 waves; each wave owns 16 Q-rows; block covers 64 Q-rows of one (b,h).
// K: (B,NKV,Nk,64) row-major. V: (B,NKV,64,Nk) (pre-transposed). Q: (B,NH,Nq,64).
// O: (B,Nq,NH,64). KV staged in 64-key LDS tiles, rows padded to 72 (full-BW b128 reads).
// Fragment layouts identical to k_mm (A: row=l15,k=quad*8+j; B: col=l15,k=quad*8+j;
// C: row=quad*4+r, col=l15). P re-fragmented through wave-private LDS tile (no barrier).
__global__ __launch_bounds__(256) void k_fattn(const ushort* __restrict__ Q, const ushort* __restrict__ K,
                      const ushort* __restrict__ V, ushort* __restrict__ O,
                      int NH, int NKV, int Nq, int Nk, float scale){
  __shared__ ushort Kt[64*72];     // [key][hd]
  __shared__ ushort Vt[64*72];     // [hd][key]
  __shared__ ushort Ps[4][16*72];  // per-wave [q][key]
  int tid = threadIdx.x, lane = tid & 63, wv = tid >> 6;
  int l15 = lane & 15, quad = lane >> 4;
  int nqt = Nq >> 6;
  int qt = blockIdx.x % nqt; int t = blockIdx.x / nqt; int h = t % NH; int b = t / NH;
  int kvh = h / (NH / NKV);
  const ushort* Kb = K + (size_t)(b*NKV+kvh)*Nk*64;
  const ushort* Vb = V + (size_t)(b*NKV+kvh)*64*Nk;
  // Q fragments: wave rows qt*64 + wv*16 + l15, k split in two 32-chunks
  const ushort* Qp = Q + ((size_t)((b*NH+h)*Nq + qt*64 + wv*16 + l15))*64;
  bf16x8 qf0 = __builtin_bit_cast(bf16x8, *(const uint4*)(Qp + quad*8));
  bf16x8 qf1 = __builtin_bit_cast(bf16x8, *(const uint4*)(Qp + 32 + quad*8));
  f32x4 acc[4] = {};
  float m_run[4] = {-1e30f,-1e30f,-1e30f,-1e30f};
  float l_run[4] = {0.f,0.f,0.f,0.f};
  ushort* Pw = Ps[wv];
  for (int t0 = 0; t0 < Nk; t0 += 64){
    // stage 64 keys of K [key][hd] and V [hd][key] (both 64x64 bf16)
    #pragma unroll
    for (int i = 0; i < 2; ++i){
      int c = tid + i*256; int row = c >> 3; int k8 = (c & 7) << 3;
      *(uint4*)(Kt + row*72 + k8) = *(const uint4*)(Kb + (size_t)(t0+row)*64 + k8);
      *(uint4*)(Vt + row*72 + k8) = *(const uint4*)(Vb + (size_t)row*Nk + t0 + k8);
    }
    __syncthreads();
    // S = Q @ K^T : 4 col-tiles (16 keys each) x 2 k-steps
    f32x4 s[4] = {};
    #pragma unroll
    for (int nj = 0; nj < 4; ++nj){
      bf16x8 kf0 = __builtin_bit_cast(bf16x8, *(const uint4*)(Kt + (nj*16+l15)*72 + quad*8));
      s[nj] = __builtin_amdgcn_mfma_f32_16x16x32_bf16(qf0, kf0, s[nj], 0, 0, 0);
      bf16x8 kf1 = __builtin_bit_cast(bf16x8, *(const uint4*)(Kt + (nj*16+l15)*72 + 32 + quad*8));
      s[nj] = __builtin_amdgcn_mfma_f32_16x16x32_bf16(qf1, kf1, s[nj], 0, 0, 0);
    }
    #pragma unroll
    for (int nj = 0; nj < 4; ++nj)
      #pragma unroll
      for (int r = 0; r < 4; ++r) s[nj][r] *= scale;
    // online softmax; row = quad*4+r, cols spread over l15 within the quad group
    float al[4];
    #pragma unroll
    for (int r = 0; r < 4; ++r){
      float tm = fmaxf(fmaxf(s[0][r], s[1][r]), fmaxf(s[2][r], s[3][r]));
      #pragma unroll
      for (int off = 8; off; off >>= 1) tm = fmaxf(tm, __shfl_xor(tm, off, 64));
      float mn = fmaxf(m_run[r], tm);
      al[r] = expf(m_run[r] - mn);
      m_run[r] = mn;
      float ts = 0.f;
      #pragma unroll
      for (int nj = 0; nj < 4; ++nj){ float p = expf(s[nj][r] - mn); s[nj][r] = p; ts += p; }
      #pragma unroll
      for (int off = 8; off; off >>= 1) ts += __shfl_xor(ts, off, 64);
      l_run[r] = l_run[r]*al[r] + ts;
    }
    // rescale O, write P tile (wave-private; same-wave LDS ordering, no barrier)
    #pragma unroll
    for (int nj = 0; nj < 4; ++nj){
      #pragma unroll
      for (int r = 0; r < 4; ++r){
        acc[nj][r] *= al[r];
        Pw[(quad*4+r)*72 + nj*16 + l15] = fbits(s[nj][r]);
      }
    }
    // O += P @ V
    bf16x8 pf0 = __builtin_bit_cast(bf16x8, *(const uint4*)(Pw + l15*72 + quad*8));
    bf16x8 pf1 = __builtin_bit_cast(bf16x8, *(const uint4*)(Pw + l15*72 + 32 + quad*8));
    #pragma unroll
    for (int nj = 0; nj < 4; ++nj){
      bf16x8 vf0 = __builtin_bit_cast(bf16x8, *(const uint4*)(Vt + (nj*16+l15)*72 + quad*8));
      acc[nj] = __builtin_amdgcn_mfma_f32_16x16x32_bf16(pf0, vf0, acc[nj], 0, 0, 0);
      bf16x8 vf1 = __builtin_bit_cast(bf16x8, *(const uint4*)(Vt + (nj*16+l15)*72 + 32 + quad*8));
      acc[nj] = __builtin_amdgcn_mfma_f32_16x16x32_bf16(pf1, vf1, acc[nj], 0, 0, 0);
    }
    __syncthreads();
  }
  float inv[4];
  #pragma unroll
  for (int r = 0; r < 4; ++r) inv[r] = 1.f / l_run[r];
  int nbase = qt*64 + wv*16 + quad*4;
  #pragma unroll
  for (int r = 0; r < 4; ++r){
    size_t ob = ((size_t)((b*Nq + nbase + r)*NH + h))*64;
    #pragma unroll
    for (int nj = 0; nj < 4; ++nj)
      O[ob + nj*16 + l15] = fbits(acc[nj][r]*inv[r]);
  }
}

// ---------- residual: X += (mod? g[b,d] : 1) * val ----------
__global__ void k_resid(float* __restrict__ X, const bf16* __restrict__ val,
                        const float* __restrict__ mod, int goff, int n){
  int i = blockIdx.x*256 + threadIdx.x;
  if (i >= n) return;
  float g = 1.f;
  if (mod){ int b = i >> 20; int d = i & 1023; g = mod[b*6144 + goff + d]; }
  X[i] += g*bf2f(val[i]);
}

// ---------- concat [X(fp32), VST(bf16)] -> CAT bf16 ----------
__global__ void k_concat(const float* __restrict__ X, const bf16* __restrict__ V,
                         bf16* __restrict__ C, int n){
  int i = blockIdx.x*256 + threadIdx.x;
  if (i >= n) return;
  int row = i >> 11, col = i & 2047;
  C[i] = (col < 1024) ? f2bf(X[(size_t)row*1024 + col]) : V[(size_t)row*1024 + col - 1024];
}

// ---------- integrator control update ----------
__global__ void k_ctrl(const bf16* __restrict__ ctrl, const float* __restrict__ X,
                       bf16* __restrict__ VST, bf16* __restrict__ XN,
                       const float* __restrict__ mu, int n){
  int i = blockIdx.x*256 + threadIdx.x;
  if (i >= n) return;
  int row = i >> 10, d = i & 1023;
  const bf16* cr = ctrl + (size_t)row*3072;
  float alpha = sigmf_(bf2f(cr[d]));
  float braw  = bf2f(cr[1024 + d]);
  float beta  = fmaxf(braw, 0.f) + log1pf(expf(-fabsf(braw)));
  float gate  = sigmf_(bf2f(cr[2048 + d]));
  float vn = alpha*bf2f(VST[i]) - beta*(X[i] - mu[d]);
  VST[i] = f2bf(vn);
  XN[i]  = f2bf(X[i] + 0.1f*gate*vn);
}

// ---------- hg2: hp = sigmoid(hg1out @ w + b) ; fp32 halt tail ----------
__global__ __launch_bounds__(64) void k_hg2(const bf16* __restrict__ hin, const float* __restrict__ w,
                     const float* __restrict__ bb, float* __restrict__ hp,
                     float* __restrict__ oout, int it){
  int r = blockIdx.x; int lane = threadIdx.x;
  const bf16* hr = hin + (size_t)r*256;
  float s = 0.f;
  #pragma unroll
  for (int i = 0; i < 4; ++i) s += bf2f(hr[lane + i*64])*w[lane + i*64];
  for (int off = 32; off; off >>= 1) s += __shfl_xor(s, off, 64);
  if (lane == 0){
    float v = sigmf_(s + bb[0]);
    hp[r] = v;
    int b = r >> 10, nn = r & 1023;
    oout[((size_t)(b*2 + it) << 10) + nn] = v;
  }
}

// ---------- integ += hp * refined * int_w ----------
__global__ void k_integ(float* __restrict__ X, const float* __restrict__ hp,
                        const bf16* __restrict__ rf, const float* __restrict__ iw, int n){
  int i = blockIdx.x*256 + threadIdx.x;
  if (i >= n) return;
  int row = i >> 10, d = i & 1023;
  X[i] += hp[row]*bf2f(rf[i])*iw[d];
}

extern "C" void kernel_launch(void* const* d_in, const int* in_sizes, int n_in,
                              void* d_out, int out_size, void* d_ws, size_t ws_size,
                              hipStream_t stream) {
  const float* x_in  = (const float*)d_in[0];
  const float* c_in  = (const float*)d_in[1];
  const float* ctx_in= (const float*)d_in[2];
  const float* cosw  = (const float*)d_in[3];
  const float* sinw  = (const float*)d_in[4];
  const float* wq    = (const float*)d_in[5];
  const float* wk    = (const float*)d_in[6];
  const float* wv    = (const float*)d_in[7];
  const float* wo    = (const float*)d_in[8];
  const float* cwq   = (const float*)d_in[9];
  const float* cwk   = (const float*)d_in[10];
  const float* cwv   = (const float*)d_in[11];
  const float* cwo   = (const float*)d_in[12];
  const float* fc1_w = (const float*)d_in[13];
  const float* fc1_b = (const float*)d_in[14];
  const float* fc2_w = (const float*)d_in[15];
  const float* fc2_b = (const float*)d_in[16];
  const float* ada_w = (const float*)d_in[17];
  const float* ada_b = (const float*)d_in[18];
  const float* n1    = (const float*)d_in[19];
  const float* n2    = (const float*)d_in[20];
  const float* n3    = (const float*)d_in[21];
  const float* int_w = (const float*)d_in[22];
  const float* mu    = (const float*)d_in[23];
  const float* hg1_w = (const float*)d_in[24];
  const float* hg1_b = (const float*)d_in[25];
  const float* hg2_w = (const float*)d_in[26];
  const float* hg2_b = (const float*)d_in[27];
  const float* ct1_w = (const float*)d_in[28];
  const float* ct1_b = (const float*)d_in[29];
  const float* ct2_w = (const float*)d_in[30];
  const float* ct2_b = (const float*)d_in[31];
  const float* rf1_w = (const float*)d_in[32];
  const float* rf1_b = (const float*)d_in[33];
  const float* rf2_w = (const float*)d_in[34];
  const float* rf2_b = (const float*)d_in[35];

  float* out_f  = (float*)d_out;
  float* out_hp = out_f + (size_t)BB*NN*DD;

  // ---- workspace map (~64.2 MB) ----
  char* wsb = (char*)d_ws;
  const size_t Mi = 1u << 20;
  float* X  = (float*)wsb;                    // [0,16MB)
  bf16*  Hh = (bf16*)(wsb + 16*Mi);           // [16,24MB)
  bf16*  Qb = (bf16*)(wsb + 24*Mi);           // [24,32MB)
  bf16*  R  = (bf16*)(wsb + 32*Mi);           // [32,64MB)
  bf16*  QR  = R;
  bf16*  SAb = R + 4*Mi;
  bf16*  KP  = R + 8*Mi;
  bf16*  VP  = R + 9*Mi;
  bf16*  KR  = R + 10*Mi;
  bf16*  VR  = R + 11*Mi;
  bf16*  CTXB= R + 12*Mi;
  bf16*  BIG = R;
  bf16*  CT1 = R + 12*Mi;
  bf16*  HG1 = R + 12*Mi;
  bf16*  RFO = R + 8*Mi;
  float* SIL = (float*)(wsb + 64*Mi);
  float* MOD = SIL + 4096;
  float* HP  = MOD + 24576;
  bf16*  VST = Qb;
  bf16*  XN  = Hh;

  const int NT = BB*NN*DD;
  const float scale = 0.125f;
  #define G1(n) dim3(((n)+255)/256), dim3(256)
  #define MM(Aptr,Bptr,biasptr,Cptr,M,N,K,act) \
    k_mm<<<dim3((N)/128,(M)/128), dim3(256), 0, stream>>>((const ushort*)(Aptr),(Bptr),(biasptr),(ushort*)(Cptr),(M),(N),(K),(act))

  // x -> X; mod = silu(c) @ ada_w + ada_b
  k_copy4<<<G1(NT/4), 0, stream>>>((const float4*)x_in, (float4*)X, NT/4);
  k_silu<<<G1(BB*DD), 0, stream>>>(c_in, SIL, BB*DD);
  k_ada<<<dim3(96), dim3(256), 0, stream>>>(SIL, ada_w, ada_b, MOD);

  // ---- self-attention ----
  k_rms<<<dim3(4096), dim3(256), 0, stream>>>(X, n1, MOD, DD, 0, Hh, 1);
  MM(Hh, wq, nullptr, Qb, 4096, 1024, 1024, 0);
  MM(Hh, wk, nullptr, KP, 4096, 256, 1024, 0);
  MM(Hh, wv, nullptr, VP, 4096, 256, 1024, 0);
  k_rope<<<G1(BB*HH*NN*32), 0, stream>>>(Qb, cosw, sinw, QR, HH, BB*HH*NN*32);
  k_rope<<<G1(BB*KVH*NN*32), 0, stream>>>(KP, cosw, sinw, KR, KVH, BB*KVH*NN*32);
  k_trv<<<G1(BB*NN*KVH*64), 0, stream>>>(VP, VR, NN, KVH, BB*NN*KVH*64);
  k_fattn<<<dim3(BB*HH*(NN/64)), dim3(256), 0, stream>>>((const ushort*)QR, (const ushort*)KR,
      (const ushort*)VR, (ushort*)SAb, HH, KVH, NN, NN, scale);
  MM(SAb, wo, nullptr, Hh, 4096, 1024, 1024, 0);
  k_resid<<<G1(NT), 0, stream>>>(X, Hh, MOD, 2*DD, NT);

  // ---- cross-attention ----
  k_rms<<<dim3(4096), dim3(256), 0, stream>>>(X, n2, nullptr, 0, 0, Hh, 0);
  MM(Hh, cwq, nullptr, Qb, 4096, 1024, 1024, 0);
  k_tr<<<G1(NT), 0, stream>>>(Qb, QR, NN, HH, NT);
  k_f2bfv<<<G1(BB*SS*CTXD), 0, stream>>>(ctx_in, CTXB, BB*SS*CTXD);
  MM(CTXB, cwk, nullptr, KP, 512, 1024, 2048, 0);
  MM(CTXB, cwv, nullptr, VP, 512, 1024, 2048, 0);
  k_tr<<<G1(BB*SS*HH*64), 0, stream>>>(KP, KR, SS, HH, BB*SS*HH*64);
  k_trv<<<G1(BB*SS*HH*64), 0, stream>>>(VP, VR, SS, HH, BB*SS*HH*64);
  k_fattn<<<dim3(BB*HH*(NN/64)), dim3(256), 0, stream>>>((const ushort*)QR, (const ushort*)KR,
      (const ushort*)VR, (ushort*)SAb, HH, HH, NN, SS, scale);
  MM(SAb, cwo, nullptr, Hh, 4096, 1024, 1024, 0);
  k_resid<<<G1(NT), 0, stream>>>(X, Hh, nullptr, 0, NT);

  // ---- MLP ----
  k_rms<<<dim3(4096), dim3(256), 0, stream>>>(X, n3, MOD, 4*DD, 3*DD, Hh, 1);
  MM(Hh, fc1_w, fc1_b, BIG, 4096, 4096, 1024, 1);
  MM(BIG, fc2_w, fc2_b, Qb, 4096, 1024, 4096, 0);
  k_resid<<<G1(NT), 0, stream>>>(X, Qb, MOD, 5*DD, NT);

  // ---- integrator (NITER=2) ----
  k_zero16<<<G1(NT), 0, stream>>>((unsigned short*)VST, NT);
  for (int it = 0; it < 2; ++it){
    k_concat<<<G1(2*NT), 0, stream>>>(X, VST, BIG, 2*NT);
    MM(BIG, ct1_w, ct1_b, CT1, 4096, 512, 2048, 1);
    MM(CT1, ct2_w, ct2_b, BIG, 4096, 3072, 512, 0);
    k_ctrl<<<G1(NT), 0, stream>>>(BIG, X, VST, XN, mu, NT);
    MM(XN, hg1_w, hg1_b, HG1, 4096, 256, 1024, 1);
    k_hg2<<<dim3(4096), dim3(64), 0, stream>>>(HG1, hg2_w, hg2_b, HP, out_hp, it);
    MM(XN, rf1_w, rf1_b, BIG, 4096, 2048, 1024, 1);
    MM(BIG, rf2_w, rf2_b, RFO, 4096, 1024, 2048, 0);
    k_integ<<<G1(NT), 0, stream>>>(X, HP, RFO, int_w, NT);
  }
  // ---- final output: FP32 ----
  k_copy4<<<G1(NT/4), 0, stream>>>((const float4*)X, (float4*)out_f, NT/4);
  #undef G1
  #undef MM
}

// Round 3
// 1285.380 us; speedup vs baseline: 1.9599x; 1.4074x over previous
//
#include <hip/hip_runtime.h>
#include <hip/hip_bf16.h>
#include <math.h>

typedef __hip_bfloat16 bf16;
typedef unsigned short ushort;
typedef __bf16 bf16x8 __attribute__((ext_vector_type(8)));
typedef unsigned short u16x8 __attribute__((ext_vector_type(8)));
typedef float f32x4 __attribute__((ext_vector_type(4)));

#define BB 4
#define NN 1024
#define DD 1024
#define HH 16
#define KVH 4
#define HDIM 64
#define SS 128
#define CTXD 2048
#define MLPDIM 4096

__device__ __forceinline__ float bf2f(bf16 v){ return __bfloat162float(v); }
__device__ __forceinline__ bf16 f2bf(float v){ return __float2bfloat16(v); }
__device__ __forceinline__ ushort fbits(float v){ bf16 h = __float2bfloat16(v); return *(ushort*)&h; }
__device__ __forceinline__ float ubf(ushort u){ unsigned int x = ((unsigned int)u) << 16; float f; *(unsigned int*)&f = x; return f; }
__device__ __forceinline__ float sigmf_(float x){ return 1.f/(1.f+expf(-x)); }
__device__ __forceinline__ float geluf_(float x){ return 0.5f*x*(1.f+erff(x*0.70710678118f)); }

// async global->LDS, 16B per lane; LDS dest = base + lane*16 (wave-uniform base)
typedef const __attribute__((address_space(1))) void* gas_t;
typedef __attribute__((address_space(3))) void* las_t;
__device__ __forceinline__ void gl2lds16(const void* g, void* l){
  __builtin_amdgcn_global_load_lds((gas_t)g, (las_t)l, 16, 0, 0);
}

// ---------- converts ----------
__global__ void k_copy4(const float4* __restrict__ in, float4* __restrict__ out, int n4){
  int i = blockIdx.x*256 + threadIdx.x;
  if (i < n4) out[i] = in[i];
}
__global__ void k_f2bfv(const float* __restrict__ in, bf16* __restrict__ out, int n){
  int i = blockIdx.x*256 + threadIdx.x;
  if (i < n) out[i] = f2bf(in[i]);
}
__global__ void k_silu(const float* __restrict__ c, float* __restrict__ out, int n){
  int i = blockIdx.x*256 + threadIdx.x;
  if (i < n){ float v = c[i]; out[i] = v*sigmf_(v); }
}
__global__ void k_zero16(unsigned short* __restrict__ p, int n){
  int i = blockIdx.x*256 + threadIdx.x;
  if (i < n) p[i] = 0;
}

// ---------- weight transpose+convert: in fp32 [K][N] -> out bf16 [N][K] ----------
__global__ __launch_bounds__(256) void k_wt(const float* __restrict__ in, bf16* __restrict__ out, int K, int N){
  __shared__ float t[64][65];
  int bn = blockIdx.x*64, bk = blockIdx.y*64;
  int tid = threadIdx.x;
  int c4 = (tid & 15)*4, r = tid >> 4;
  #pragma unroll
  for (int i = 0; i < 4; ++i){
    float4 v = *(const float4*)(in + (size_t)(bk + r + i*16)*N + bn + c4);
    t[c4+0][r+i*16] = v.x; t[c4+1][r+i*16] = v.y; t[c4+2][r+i*16] = v.z; t[c4+3][r+i*16] = v.w;
  }
  __syncthreads();
  int n = tid >> 2, k16 = (tid & 3)*16;
  bf16* orow = out + (size_t)(bn + n)*K + bk + k16;
  #pragma unroll
  for (int j = 0; j < 16; ++j) orow[j] = f2bf(t[n][k16 + j]);
}

// ---------- adaLN: mod = silu(c) @ ada_w + ada_b ----------
__global__ void k_ada(const float* __restrict__ sc, const float* __restrict__ w,
                      const float* __restrict__ b, float* __restrict__ mod){
  int idx = blockIdx.x*256 + threadIdx.x;  // < 4*6144
  int bb = idx / 6144, col = idx % 6144;
  const float* cp = sc + bb*DD;
  float s = 0.f;
  for (int k = 0; k < DD; ++k) s += cp[k]*w[(size_t)k*6144 + col];
  mod[idx] = s + b[col];
}

// ---------- RMSNorm (+optional adaLN scale/shift) ----------
__global__ __launch_bounds__(256) void k_rms(const float* __restrict__ X, const float* __restrict__ w,
                      const float* __restrict__ mod, int sc_off, int sh_off,
                      bf16* __restrict__ out, int use_mod){
  __shared__ float red[256];
  int row = blockIdx.x;
  int b = row >> 10;
  int tid = threadIdx.x;
  const float* xr = X + (size_t)row*DD;
  float s = 0.f;
  #pragma unroll
  for (int i = 0; i < 4; ++i){ float v = xr[tid + i*256]; s += v*v; }
  red[tid] = s; __syncthreads();
  for (int st = 128; st > 0; st >>= 1){ if (tid < st) red[tid] += red[tid+st]; __syncthreads(); }
  float rstd = rsqrtf(red[0]*(1.f/DD) + 1e-6f);
  bf16* orow = out + (size_t)row*DD;
  const float* mrow = use_mod ? (mod + (size_t)b*6*DD) : nullptr;
  #pragma unroll
  for (int i = 0; i < 4; ++i){
    int d = tid + i*256;
    float v = xr[d]*rstd*w[d];
    if (use_mod) v = v*(1.f + mrow[sc_off + d]) + mrow[sh_off + d];
    orow[d] = f2bf(v);
  }
}

// ---------- MFMA GEMM v2: C(MxN,bf16) = A(MxK,bf16) @ BT(NxK,bf16)^T [+bias][gelu] ----------
// m97 structure: 128x128 tile, BK=64, both operands staged via global_load_lds (16B),
// linear LDS dest + inverse-XOR-swizzled global source (rule 21); fragment reads are
// ds_read_b128 with matching XOR swizzle (T2). Each wave stages 32 rows (4 calls/operand).
// M%128==0, N%128==0, K%64==0. Block 256 = 4 waves, each wave 64x64.
__global__ __launch_bounds__(256,2) void k_mm2(const ushort* __restrict__ A, const ushort* __restrict__ BT,
                      const float* __restrict__ bias, ushort* __restrict__ C,
                      int M, int N, int K, int act){
  __shared__ ushort As[128*64];   // phys [row][kphys]; logical k-slot t at phys slot t^(row&7)
  __shared__ ushort Bs[128*64];
  int tid = threadIdx.x, lane = tid & 63, wv = tid >> 6;
  int l15 = lane & 15, quad = lane >> 4;
  int bm = blockIdx.y*128, bn = blockIdx.x*128;
  int wm = (wv & 1)*64, wn = (wv >> 1)*64;
  int lr = lane >> 3, lc = lane & 7;       // staging sub-row (0..7) / 16B-slot (0..7)
  int ksw = (lc ^ lr) << 3;                // inverse-swizzled source k-offset (ushorts)
  f32x4 acc[4][4] = {};
  // wave wv stages phys rows wv*32 + i*8 + lr, i=0..3
  const ushort* Abase = A  + (size_t)(bm + wv*32 + lr)*K + ksw;
  const ushort* Bbase = BT + (size_t)(bn + wv*32 + lr)*K + ksw;
  ushort* AsW = As + wv*2048;              // 32 rows * 64
  ushort* BsW = Bs + wv*2048;
  int swr = (l15 & 7) << 3;                // read-side XOR term (row&7)<<3
  for (int k0 = 0; k0 < K; k0 += 64){
    #pragma unroll
    for (int i = 0; i < 4; ++i){
      gl2lds16(Abase + k0 + (size_t)(i*8)*K, AsW + i*512);
      gl2lds16(Bbase + k0 + (size_t)(i*8)*K, BsW + i*512);
    }
    __syncthreads();   // compiler drains vmcnt before s_barrier
    #pragma unroll
    for (int ks = 0; ks < 2; ++ks){
      bf16x8 af[4], bfr[4];
      #pragma unroll
      for (int mi = 0; mi < 4; ++mi){
        int r = wm + mi*16 + l15;
        af[mi] = __builtin_bit_cast(bf16x8, *(const uint4*)(As + r*64 + ((ks*32 + quad*8) ^ swr)));
      }
      #pragma unroll
      for (int nj = 0; nj < 4; ++nj){
        int r = wn + nj*16 + l15;
        bfr[nj] = __builtin_bit_cast(bf16x8, *(const uint4*)(Bs + r*64 + ((ks*32 + quad*8) ^ swr)));
      }
      #pragma unroll
      for (int mi = 0; mi < 4; ++mi)
        #pragma unroll
        for (int nj = 0; nj < 4; ++nj)
          acc[mi][nj] = __builtin_amdgcn_mfma_f32_16x16x32_bf16(af[mi], bfr[nj], acc[mi][nj], 0, 0, 0);
    }
    __syncthreads();
  }
  // epilogue: C/D layout col=lane&15, row=quad*4+r
  #pragma unroll
  for (int nj = 0; nj < 4; ++nj){
    int col = bn + wn + nj*16 + l15;
    float bv = bias ? bias[col] : 0.f;
    #pragma unroll
    for (int mi = 0; mi < 4; ++mi){
      #pragma unroll
      for (int r = 0; r < 4; ++r){
        int row = bm + wm + mi*16 + quad*4 + r;
        float v = acc[mi][nj][r] + bv;
        if (act) v = geluf_(v);
        C[(size_t)row*N + col] = fbits(v);
      }
    }
  }
}

// ---------- RoPE: in (B,NN,NHp,64) -> out (B,NHp,NN,64), rotated ----------
__global__ void k_rope(const bf16* __restrict__ in, const float* __restrict__ cw,
                       const float* __restrict__ sw, bf16* __restrict__ out, int NHp, int n){
  int idx = blockIdx.x*256 + threadIdx.x;
  if (idx >= n) return;
  int d2 = idx & 31; int t = idx >> 5;
  int nn = t % NN; t /= NN; int h = t % NHp; int b = t / NHp;
  const bf16* base = in + ((size_t)((b*NN+nn)*NHp + h))*HDIM;
  float e = bf2f(base[2*d2]), o = bf2f(base[2*d2+1]);
  float c = cw[nn*32 + d2], s = sw[nn*32 + d2];
  bf16* ob = out + ((size_t)((b*NHp+h)*NN + nn))*HDIM;
  ob[d2]      = f2bf(e*c - o*s);
  ob[32 + d2] = f2bf(e*s + o*c);
}

// ---------- transpose (B,T,NHp,64) -> (B,NHp,T,64) ----------
__global__ void k_tr(const bf16* __restrict__ in, bf16* __restrict__ out, int T, int NHp, int n){
  int idx = blockIdx.x*256 + threadIdx.x;
  if (idx >= n) return;
  int d = idx & 63; int t = idx >> 6;
  int h = t % NHp; t /= NHp; int tok = t % T; int b = t / T;
  out[((size_t)((b*NHp+h)*T + tok))*64 + d] = in[idx];
}

// ---------- V transpose (B,T,NHp,64) -> (B,NHp,64,T) for MFMA PV B-fragments ----------
__global__ void k_trv(const bf16* __restrict__ in, bf16* __restrict__ out, int T, int NHp, int n){
  int idx = blockIdx.x*256 + threadIdx.x;
  if (idx >= n) return;
  int d = idx & 63; int t = idx >> 6;
  int h = t % NHp; t /= NHp; int tok = t % T; int b = t / T;
  out[((size_t)(b*NHp+h)*64 + d)*T + tok] = in[idx];
}

// ---------- MFMA flash attention ----------
__global__ __launch_bounds__(256) void k_fattn(const ushort* __restrict__ Q, const ushort* __restrict__ K,
                      const ushort* __restrict__ V, ushort* __restrict__ O,
                      int NH, int NKV, int Nq, int Nk, float scale){
  __shared__ ushort Kt[64*72];     // [key][hd]
  __shared__ ushort Vt[64*72];     // [hd][key]
  __shared__ ushort Ps[4][16*72];  // per-wave [q][key]
  int tid = threadIdx.x, lane = tid & 63, wv = tid >> 6;
  int l15 = lane & 15, quad = lane >> 4;
  int nqt = Nq >> 6;
  int qt = blockIdx.x % nqt; int t = blockIdx.x / nqt; int h = t % NH; int b = t / NH;
  int kvh = h / (NH / NKV);
  const ushort* Kb = K + (size_t)(b*NKV+kvh)*Nk*64;
  const ushort* Vb = V + (size_t)(b*NKV+kvh)*64*Nk;
  const ushort* Qp = Q + ((size_t)((b*NH+h)*Nq + qt*64 + wv*16 + l15))*64;
  bf16x8 qf0 = __builtin_bit_cast(bf16x8, *(const uint4*)(Qp + quad*8));
  bf16x8 qf1 = __builtin_bit_cast(bf16x8, *(const uint4*)(Qp + 32 + quad*8));
  f32x4 acc[4] = {};
  float m_run[4] = {-1e30f,-1e30f,-1e30f,-1e30f};
  float l_run[4] = {0.f,0.f,0.f,0.f};
  ushort* Pw = Ps[wv];
  for (int t0 = 0; t0 < Nk; t0 += 64){
    #pragma unroll
    for (int i = 0; i < 2; ++i){
      int c = tid + i*256; int row = c >> 3; int k8 = (c & 7) << 3;
      *(uint4*)(Kt + row*72 + k8) = *(const uint4*)(Kb + (size_t)(t0+row)*64 + k8);
      *(uint4*)(Vt + row*72 + k8) = *(const uint4*)(Vb + (size_t)row*Nk + t0 + k8);
    }
    __syncthreads();
    f32x4 s[4] = {};
    #pragma unroll
    for (int nj = 0; nj < 4; ++nj){
      bf16x8 kf0 = __builtin_bit_cast(bf16x8, *(const uint4*)(Kt + (nj*16+l15)*72 + quad*8));
      s[nj] = __builtin_amdgcn_mfma_f32_16x16x32_bf16(qf0, kf0, s[nj], 0, 0, 0);
      bf16x8 kf1 = __builtin_bit_cast(bf16x8, *(const uint4*)(Kt + (nj*16+l15)*72 + 32 + quad*8));
      s[nj] = __builtin_amdgcn_mfma_f32_16x16x32_bf16(qf1, kf1, s[nj], 0, 0, 0);
    }
    #pragma unroll
    for (int nj = 0; nj < 4; ++nj)
      #pragma unroll
      for (int r = 0; r < 4; ++r) s[nj][r] *= scale;
    float al[4];
    #pragma unroll
    for (int r = 0; r < 4; ++r){
      float tm = fmaxf(fmaxf(s[0][r], s[1][r]), fmaxf(s[2][r], s[3][r]));
      #pragma unroll
      for (int off = 8; off; off >>= 1) tm = fmaxf(tm, __shfl_xor(tm, off, 64));
      float mn = fmaxf(m_run[r], tm);
      al[r] = expf(m_run[r] - mn);
      m_run[r] = mn;
      float ts = 0.f;
      #pragma unroll
      for (int nj = 0; nj < 4; ++nj){ float p = expf(s[nj][r] - mn); s[nj][r] = p; ts += p; }
      #pragma unroll
      for (int off = 8; off; off >>= 1) ts += __shfl_xor(ts, off, 64);
      l_run[r] = l_run[r]*al[r] + ts;
    }
    #pragma unroll
    for (int nj = 0; nj < 4; ++nj){
      #pragma unroll
      for (int r = 0; r < 4; ++r){
        acc[nj][r] *= al[r];
        Pw[(quad*4+r)*72 + nj*16 + l15] = fbits(s[nj][r]);
      }
    }
    bf16x8 pf0 = __builtin_bit_cast(bf16x8, *(const uint4*)(Pw + l15*72 + quad*8));
    bf16x8 pf1 = __builtin_bit_cast(bf16x8, *(const uint4*)(Pw + l15*72 + 32 + quad*8));
    #pragma unroll
    for (int nj = 0; nj < 4; ++nj){
      bf16x8 vf0 = __builtin_bit_cast(bf16x8, *(const uint4*)(Vt + (nj*16+l15)*72 + quad*8));
      acc[nj] = __builtin_amdgcn_mfma_f32_16x16x32_bf16(pf0, vf0, acc[nj], 0, 0, 0);
      bf16x8 vf1 = __builtin_bit_cast(bf16x8, *(const uint4*)(Vt + (nj*16+l15)*72 + 32 + quad*8));
      acc[nj] = __builtin_amdgcn_mfma_f32_16x16x32_bf16(pf1, vf1, acc[nj], 0, 0, 0);
    }
    __syncthreads();
  }
  float inv[4];
  #pragma unroll
  for (int r = 0; r < 4; ++r) inv[r] = 1.f / l_run[r];
  int nbase = qt*64 + wv*16 + quad*4;
  #pragma unroll
  for (int r = 0; r < 4; ++r){
    size_t ob = ((size_t)((b*Nq + nbase + r)*NH + h))*64;
    #pragma unroll
    for (int nj = 0; nj < 4; ++nj)
      O[ob + nj*16 + l15] = fbits(acc[nj][r]*inv[r]);
  }
}

// ---------- residual: X += (mod? g[b,d] : 1) * val ----------
__global__ void k_resid(float* __restrict__ X, const bf16* __restrict__ val,
                        const float* __restrict__ mod, int goff, int n){
  int i = blockIdx.x*256 + threadIdx.x;
  if (i >= n) return;
  float g = 1.f;
  if (mod){ int b = i >> 20; int d = i & 1023; g = mod[b*6144 + goff + d]; }
  X[i] += g*bf2f(val[i]);
}

// ---------- concat [X(fp32), VST(bf16)] -> CAT bf16 ----------
__global__ void k_concat(const float* __restrict__ X, const bf16* __restrict__ V,
                         bf16* __restrict__ C, int n){
  int i = blockIdx.x*256 + threadIdx.x;
  if (i >= n) return;
  int row = i >> 11, col = i & 2047;
  C[i] = (col < 1024) ? f2bf(X[(size_t)row*1024 + col]) : V[(size_t)row*1024 + col - 1024];
}

// ---------- integrator control update ----------
__global__ void k_ctrl(const bf16* __restrict__ ctrl, const float* __restrict__ X,
                       bf16* __restrict__ VST, bf16* __restrict__ XN,
                       const float* __restrict__ mu, int n){
  int i = blockIdx.x*256 + threadIdx.x;
  if (i >= n) return;
  int row = i >> 10, d = i & 1023;
  const bf16* cr = ctrl + (size_t)row*3072;
  float alpha = sigmf_(bf2f(cr[d]));
  float braw  = bf2f(cr[1024 + d]);
  float beta  = fmaxf(braw, 0.f) + log1pf(expf(-fabsf(braw)));
  float gate  = sigmf_(bf2f(cr[2048 + d]));
  float vn = alpha*bf2f(VST[i]) - beta*(X[i] - mu[d]);
  VST[i] = f2bf(vn);
  XN[i]  = f2bf(X[i] + 0.1f*gate*vn);
}

// ---------- hg2: hp = sigmoid(hg1out @ w + b) ; fp32 halt tail ----------
__global__ __launch_bounds__(64) void k_hg2(const bf16* __restrict__ hin, const float* __restrict__ w,
                     const float* __restrict__ bb, float* __restrict__ hp,
                     float* __restrict__ oout, int it){
  int r = blockIdx.x; int lane = threadIdx.x;
  const bf16* hr = hin + (size_t)r*256;
  float s = 0.f;
  #pragma unroll
  for (int i = 0; i < 4; ++i) s += bf2f(hr[lane + i*64])*w[lane + i*64];
  for (int off = 32; off; off >>= 1) s += __shfl_xor(s, off, 64);
  if (lane == 0){
    float v = sigmf_(s + bb[0]);
    hp[r] = v;
    int b = r >> 10, nn = r & 1023;
    oout[((size_t)(b*2 + it) << 10) + nn] = v;
  }
}

// ---------- integ += hp * refined * int_w ----------
__global__ void k_integ(float* __restrict__ X, const float* __restrict__ hp,
                        const bf16* __restrict__ rf, const float* __restrict__ iw, int n){
  int i = blockIdx.x*256 + threadIdx.x;
  if (i >= n) return;
  int row = i >> 10, d = i & 1023;
  X[i] += hp[row]*bf2f(rf[i])*iw[d];
}

extern "C" void kernel_launch(void* const* d_in, const int* in_sizes, int n_in,
                              void* d_out, int out_size, void* d_ws, size_t ws_size,
                              hipStream_t stream) {
  const float* x_in  = (const float*)d_in[0];
  const float* c_in  = (const float*)d_in[1];
  const float* ctx_in= (const float*)d_in[2];
  const float* cosw  = (const float*)d_in[3];
  const float* sinw  = (const float*)d_in[4];
  const float* wq    = (const float*)d_in[5];
  const float* wk    = (const float*)d_in[6];
  const float* wv    = (const float*)d_in[7];
  const float* wo    = (const float*)d_in[8];
  const float* cwq   = (const float*)d_in[9];
  const float* cwk   = (const float*)d_in[10];
  const float* cwv   = (const float*)d_in[11];
  const float* cwo   = (const float*)d_in[12];
  const float* fc1_w = (const float*)d_in[13];
  const float* fc1_b = (const float*)d_in[14];
  const float* fc2_w = (const float*)d_in[15];
  const float* fc2_b = (const float*)d_in[16];
  const float* ada_w = (const float*)d_in[17];
  const float* ada_b = (const float*)d_in[18];
  const float* n1    = (const float*)d_in[19];
  const float* n2    = (const float*)d_in[20];
  const float* n3    = (const float*)d_in[21];
  const float* int_w = (const float*)d_in[22];
  const float* mu    = (const float*)d_in[23];
  const float* hg1_w = (const float*)d_in[24];
  const float* hg1_b = (const float*)d_in[25];
  const float* hg2_w = (const float*)d_in[26];
  const float* hg2_b = (const float*)d_in[27];
  const float* ct1_w = (const float*)d_in[28];
  const float* ct1_b = (const float*)d_in[29];
  const float* ct2_w = (const float*)d_in[30];
  const float* ct2_b = (const float*)d_in[31];
  const float* rf1_w = (const float*)d_in[32];
  const float* rf1_b = (const float*)d_in[33];
  const float* rf2_w = (const float*)d_in[34];
  const float* rf2_b = (const float*)d_in[35];

  float* out_f  = (float*)d_out;
  float* out_hp = out_f + (size_t)BB*NN*DD;

  // ---- workspace map (~112 MB) ----
  char* wsb = (char*)d_ws;
  const size_t Mi = 1u << 20;
  float* X  = (float*)wsb;                    // [0,16MB)
  bf16*  Hh = (bf16*)(wsb + 16*Mi);           // [16,24MB)
  bf16*  Qb = (bf16*)(wsb + 24*Mi);           // [24,32MB)
  bf16*  R  = (bf16*)(wsb + 32*Mi);           // [32,64MB)
  bf16*  QR  = R;
  bf16*  SAb = R + 4*Mi;
  bf16*  KP  = R + 8*Mi;
  bf16*  VP  = R + 9*Mi;
  bf16*  KR  = R + 10*Mi;
  bf16*  VR  = R + 11*Mi;
  bf16*  CTXB= R + 12*Mi;
  bf16*  BIG = R;
  bf16*  CT1 = R + 12*Mi;
  bf16*  HG1 = R + 12*Mi;
  bf16*  RFO = R + 8*Mi;
  float* SIL = (float*)(wsb + 64*Mi);
  float* MOD = SIL + 4096;
  float* HP  = MOD + 24576;
  bf16*  VST = Qb;
  bf16*  XN  = Hh;
  // transposed bf16 weights [N][K] at +65MB (46.5MB)
  bf16* WT   = (bf16*)(wsb + 65*Mi);
  bf16* wqT  = WT;                 // 1024x1024
  bf16* wkT  = wqT  + 1048576;     // 256x1024
  bf16* wvT  = wkT  + 262144;      // 256x1024
  bf16* woT  = wvT  + 262144;      // 1024x1024
  bf16* cwqT = woT  + 1048576;     // 1024x1024
  bf16* cwkT = cwqT + 1048576;     // 1024x2048
  bf16* cwvT = cwkT + 2097152;     // 1024x2048
  bf16* cwoT = cwvT + 2097152;     // 1024x1024
  bf16* fc1T = cwoT + 1048576;     // 4096x1024
  bf16* fc2T = fc1T + 4194304;     // 1024x4096
  bf16* ct1T = fc2T + 4194304;     // 512x2048
  bf16* ct2T = ct1T + 1048576;     // 3072x512
  bf16* rf1T = ct2T + 1572864;     // 2048x1024
  bf16* rf2T = rf1T + 2097152;     // 1024x2048
  bf16* hg1T = rf2T + 2097152;     // 256x1024

  const int NT = BB*NN*DD;
  const float scale = 0.125f;
  #define G1(n) dim3(((n)+255)/256), dim3(256)
  #define WTR(src,dst,K,N) k_wt<<<dim3((N)/64,(K)/64), dim3(256), 0, stream>>>((src),(dst),(K),(N))
  #define MM(Aptr,BTptr,biasptr,Cptr,M,N,K,act) \
    k_mm2<<<dim3((N)/128,(M)/128), dim3(256), 0, stream>>>((const ushort*)(Aptr),(const ushort*)(BTptr),(biasptr),(ushort*)(Cptr),(M),(N),(K),(act))

  // ---- weight prep: fp32 [K][N] -> bf16 [N][K] ----
  WTR(wq,   wqT, 1024, 1024);
  WTR(wk,   wkT, 1024, 256);
  WTR(wv,   wvT, 1024, 256);
  WTR(wo,   woT, 1024, 1024);
  WTR(cwq,  cwqT,1024, 1024);
  WTR(cwk,  cwkT,2048, 1024);
  WTR(cwv,  cwvT,2048, 1024);
  WTR(cwo,  cwoT,1024, 1024);
  WTR(fc1_w,fc1T,1024, 4096);
  WTR(fc2_w,fc2T,4096, 1024);
  WTR(ct1_w,ct1T,2048, 512);
  WTR(ct2_w,ct2T,512,  3072);
  WTR(rf1_w,rf1T,1024, 2048);
  WTR(rf2_w,rf2T,2048, 1024);
  WTR(hg1_w,hg1T,1024, 256);

  // x -> X; mod = silu(c) @ ada_w + ada_b
  k_copy4<<<G1(NT/4), 0, stream>>>((const float4*)x_in, (float4*)X, NT/4);
  k_silu<<<G1(BB*DD), 0, stream>>>(c_in, SIL, BB*DD);
  k_ada<<<dim3(96), dim3(256), 0, stream>>>(SIL, ada_w, ada_b, MOD);

  // ---- self-attention ----
  k_rms<<<dim3(4096), dim3(256), 0, stream>>>(X, n1, MOD, DD, 0, Hh, 1);
  MM(Hh, wqT, nullptr, Qb, 4096, 1024, 1024, 0);
  MM(Hh, wkT, nullptr, KP, 4096, 256, 1024, 0);
  MM(Hh, wvT, nullptr, VP, 4096, 256, 1024, 0);
  k_rope<<<G1(BB*HH*NN*32), 0, stream>>>(Qb, cosw, sinw, QR, HH, BB*HH*NN*32);
  k_rope<<<G1(BB*KVH*NN*32), 0, stream>>>(KP, cosw, sinw, KR, KVH, BB*KVH*NN*32);
  k_trv<<<G1(BB*NN*KVH*64), 0, stream>>>(VP, VR, NN, KVH, BB*NN*KVH*64);
  k_fattn<<<dim3(BB*HH*(NN/64)), dim3(256), 0, stream>>>((const ushort*)QR, (const ushort*)KR,
      (const ushort*)VR, (ushort*)SAb, HH, KVH, NN, NN, scale);
  MM(SAb, woT, nullptr, Hh, 4096, 1024, 1024, 0);
  k_resid<<<G1(NT), 0, stream>>>(X, Hh, MOD, 2*DD, NT);

  // ---- cross-attention ----
  k_rms<<<dim3(4096), dim3(256), 0, stream>>>(X, n2, nullptr, 0, 0, Hh, 0);
  MM(Hh, cwqT, nullptr, Qb, 4096, 1024, 1024, 0);
  k_tr<<<G1(NT), 0, stream>>>(Qb, QR, NN, HH, NT);
  k_f2bfv<<<G1(BB*SS*CTXD), 0, stream>>>(ctx_in, CTXB, BB*SS*CTXD);
  MM(CTXB, cwkT, nullptr, KP, 512, 1024, 2048, 0);
  MM(CTXB, cwvT, nullptr, VP, 512, 1024, 2048, 0);
  k_tr<<<G1(BB*SS*HH*64), 0, stream>>>(KP, KR, SS, HH, BB*SS*HH*64);
  k_trv<<<G1(BB*SS*HH*64), 0, stream>>>(VP, VR, SS, HH, BB*SS*HH*64);
  k_fattn<<<dim3(BB*HH*(NN/64)), dim3(256), 0, stream>>>((const ushort*)QR, (const ushort*)KR,
      (const ushort*)VR, (ushort*)SAb, HH, HH, NN, SS, scale);
  MM(SAb, cwoT, nullptr, Hh, 4096, 1024, 1024, 0);
  k_resid<<<G1(NT), 0, stream>>>(X, Hh, nullptr, 0, NT);

  // ---- MLP ----
  k_rms<<<dim3(4096), dim3(256), 0, stream>>>(X, n3, MOD, 4*DD, 3*DD, Hh, 1);
  MM(Hh, fc1T, fc1_b, BIG, 4096, 4096, 1024, 1);
  MM(BIG, fc2T, fc2_b, Qb, 4096, 1024, 4096, 0);
  k_resid<<<G1(NT), 0, stream>>>(X, Qb, MOD, 5*DD, NT);

  // ---- integrator (NITER=2) ----
  k_zero16<<<G1(NT), 0, stream>>>((unsigned short*)VST, NT);
  for (int it = 0; it < 2; ++it){
    k_concat<<<G1(2*NT), 0, stream>>>(X, VST, BIG, 2*NT);
    MM(BIG, ct1T, ct1_b, CT1, 4096, 512, 2048, 1);
    MM(CT1, ct2T, ct2_b, BIG, 4096, 3072, 512, 0);
    k_ctrl<<<G1(NT), 0, stream>>>(BIG, X, VST, XN, mu, NT);
    MM(XN, hg1T, hg1_b, HG1, 4096, 256, 1024, 1);
    k_hg2<<<dim3(4096), dim3(64), 0, stream>>>(HG1, hg2_w, hg2_b, HP, out_hp, it);
    MM(XN, rf1T, rf1_b, BIG, 4096, 2048, 1024, 1);
    MM(BIG, rf2T, rf2_b, RFO, 4096, 1024, 2048, 0);
    k_integ<<<G1(NT), 0, stream>>>(X, HP, RFO, int_w, NT);
  }
  // ---- final output: FP32 ----
  k_copy4<<<G1(NT/4), 0, stream>>>((const float4*)X, (float4*)out_f, NT/4);
  #undef G1
  #undef WTR
  #undef MM
}

// Round 4
// 1171.555 us; speedup vs baseline: 2.1503x; 1.0972x over previous
//
#include <hip/hip_runtime.h>
#include <hip/hip_bf16.h>
#include <math.h>

typedef __hip_bfloat16 bf16;
typedef unsigned short ushort;
typedef __bf16 bf16x8 __attribute__((ext_vector_type(8)));
typedef unsigned short u16x8 __attribute__((ext_vector_type(8)));
typedef float f32x4 __attribute__((ext_vector_type(4)));

#define BB 4
#define NN 1024
#define DD 1024
#define HH 16
#define KVH 4
#define HDIM 64
#define SS 128
#define CTXD 2048
#define MLPDIM 4096

__device__ __forceinline__ float bf2f(bf16 v){ return __bfloat162float(v); }
__device__ __forceinline__ bf16 f2bf(float v){ return __float2bfloat16(v); }
__device__ __forceinline__ ushort fbits(float v){ bf16 h = __float2bfloat16(v); return *(ushort*)&h; }
__device__ __forceinline__ float ubf(ushort u){ unsigned int x = ((unsigned int)u) << 16; float f; *(unsigned int*)&f = x; return f; }
__device__ __forceinline__ float sigmf_(float x){ return 1.f/(1.f+expf(-x)); }
__device__ __forceinline__ float geluf_(float x){ return 0.5f*x*(1.f+erff(x*0.70710678118f)); }

// async global->LDS, 16B per lane; LDS dest = base + lane*16 (wave-uniform base)
typedef const __attribute__((address_space(1))) void* gas_t;
typedef __attribute__((address_space(3))) void* las_t;
__device__ __forceinline__ void gl2lds16(const void* g, void* l){
  __builtin_amdgcn_global_load_lds((gas_t)g, (las_t)l, 16, 0, 0);
}

// ---------- converts ----------
__global__ void k_copy4(const float4* __restrict__ in, float4* __restrict__ out, int n4){
  int i = blockIdx.x*256 + threadIdx.x;
  if (i < n4) out[i] = in[i];
}
__global__ void k_f2bfv(const float* __restrict__ in, bf16* __restrict__ out, int n){
  int i = blockIdx.x*256 + threadIdx.x;
  if (i < n) out[i] = f2bf(in[i]);
}
__global__ void k_silu(const float* __restrict__ c, float* __restrict__ out, int n){
  int i = blockIdx.x*256 + threadIdx.x;
  if (i < n){ float v = c[i]; out[i] = v*sigmf_(v); }
}
__global__ void k_zero16(unsigned short* __restrict__ p, int n){
  int i = blockIdx.x*256 + threadIdx.x;
  if (i < n) p[i] = 0;
}

// ---------- weight transpose+convert: in fp32 [K][N] -> out bf16 [N][K] ----------
__global__ __launch_bounds__(256) void k_wt(const float* __restrict__ in, bf16* __restrict__ out, int K, int N){
  __shared__ float t[64][65];
  int bn = blockIdx.x*64, bk = blockIdx.y*64;
  int tid = threadIdx.x;
  int c4 = (tid & 15)*4, r = tid >> 4;
  #pragma unroll
  for (int i = 0; i < 4; ++i){
    float4 v = *(const float4*)(in + (size_t)(bk + r + i*16)*N + bn + c4);
    t[c4+0][r+i*16] = v.x; t[c4+1][r+i*16] = v.y; t[c4+2][r+i*16] = v.z; t[c4+3][r+i*16] = v.w;
  }
  __syncthreads();
  int n = tid >> 2, k16 = (tid & 3)*16;
  bf16* orow = out + (size_t)(bn + n)*K + bk + k16;
  #pragma unroll
  for (int j = 0; j < 16; ++j) orow[j] = f2bf(t[n][k16 + j]);
}

// ---------- adaLN: mod = silu(c) @ ada_w + ada_b ----------
// k_adab: mod = bias broadcast. k_ada2: K-split partial GEMV, atomicAdd accumulate.
__global__ void k_adab(const float* __restrict__ b, float* __restrict__ mod, int n){
  int idx = blockIdx.x*256 + threadIdx.x;
  if (idx < n) mod[idx] = b[idx % 6144];
}
// grid (6 col-groups, 32 k-splits), block 256. Each thread: 4 cols (float4) x 4 batches,
// 32 coalesced k-steps; w read exactly once across the whole grid.
__global__ __launch_bounds__(256) void k_ada2(const float* __restrict__ sc, const float* __restrict__ w,
                       float* __restrict__ mod){
  __shared__ float sl[4][32];
  int tid = threadIdx.x;
  int col4 = blockIdx.x*1024 + tid*4;
  int k0 = blockIdx.y*32;
  if (tid < 128) sl[tid >> 5][tid & 31] = sc[(tid >> 5)*DD + k0 + (tid & 31)];
  __syncthreads();
  f32x4 acc[4] = {};
  for (int kk = 0; kk < 32; ++kk){
    const float4 wv4 = *(const float4*)(w + (size_t)(k0 + kk)*6144 + col4);
    #pragma unroll
    for (int b = 0; b < 4; ++b){
      float s = sl[b][kk];
      acc[b][0] += s*wv4.x; acc[b][1] += s*wv4.y; acc[b][2] += s*wv4.z; acc[b][3] += s*wv4.w;
    }
  }
  #pragma unroll
  for (int b = 0; b < 4; ++b)
    #pragma unroll
    for (int j = 0; j < 4; ++j)
      atomicAdd(&mod[(size_t)b*6144 + col4 + j], acc[b][j]);
}

// ---------- RMSNorm (+optional adaLN scale/shift) ----------
__global__ __launch_bounds__(256) void k_rms(const float* __restrict__ X, const float* __restrict__ w,
                      const float* __restrict__ mod, int sc_off, int sh_off,
                      bf16* __restrict__ out, int use_mod){
  __shared__ float red[256];
  int row = blockIdx.x;
  int b = row >> 10;
  int tid = threadIdx.x;
  const float* xr = X + (size_t)row*DD;
  float s = 0.f;
  #pragma unroll
  for (int i = 0; i < 4; ++i){ float v = xr[tid + i*256]; s += v*v; }
  red[tid] = s; __syncthreads();
  for (int st = 128; st > 0; st >>= 1){ if (tid < st) red[tid] += red[tid+st]; __syncthreads(); }
  float rstd = rsqrtf(red[0]*(1.f/DD) + 1e-6f);
  bf16* orow = out + (size_t)row*DD;
  const float* mrow = use_mod ? (mod + (size_t)b*6*DD) : nullptr;
  #pragma unroll
  for (int i = 0; i < 4; ++i){
    int d = tid + i*256;
    float v = xr[d]*rstd*w[d];
    if (use_mod) v = v*(1.f + mrow[sc_off + d]) + mrow[sh_off + d];
    orow[d] = f2bf(v);
  }
}

// ---------- MFMA GEMM v2: C(MxN,bf16) = A(MxK,bf16) @ BT(NxK,bf16)^T [+bias][gelu] ----------
// m97 structure: 128x128 tile, BK=64, both operands staged via global_load_lds (16B),
// linear LDS dest + inverse-XOR-swizzled global source (rule 21); fragment reads are
// ds_read_b128 with matching XOR swizzle (T2). Each wave stages 32 rows (4 calls/operand).
// M%128==0, N%128==0, K%64==0. Block 256 = 4 waves, each wave 64x64.
__global__ __launch_bounds__(256,2) void k_mm2(const ushort* __restrict__ A, const ushort* __restrict__ BT,
                      const float* __restrict__ bias, ushort* __restrict__ C,
                      int M, int N, int K, int act){
  __shared__ ushort As[128*64];   // phys [row][kphys]; logical k-slot t at phys slot t^(row&7)
  __shared__ ushort Bs[128*64];
  int tid = threadIdx.x, lane = tid & 63, wv = tid >> 6;
  int l15 = lane & 15, quad = lane >> 4;
  int bm = blockIdx.y*128, bn = blockIdx.x*128;
  int wm = (wv & 1)*64, wn = (wv >> 1)*64;
  int lr = lane >> 3, lc = lane & 7;       // staging sub-row (0..7) / 16B-slot (0..7)
  int ksw = (lc ^ lr) << 3;                // inverse-swizzled source k-offset (ushorts)
  f32x4 acc[4][4] = {};
  // wave wv stages phys rows wv*32 + i*8 + lr, i=0..3
  const ushort* Abase = A  + (size_t)(bm + wv*32 + lr)*K + ksw;
  const ushort* Bbase = BT + (size_t)(bn + wv*32 + lr)*K + ksw;
  ushort* AsW = As + wv*2048;              // 32 rows * 64
  ushort* BsW = Bs + wv*2048;
  int swr = (l15 & 7) << 3;                // read-side XOR term (row&7)<<3
  for (int k0 = 0; k0 < K; k0 += 64){
    #pragma unroll
    for (int i = 0; i < 4; ++i){
      gl2lds16(Abase + k0 + (size_t)(i*8)*K, AsW + i*512);
      gl2lds16(Bbase + k0 + (size_t)(i*8)*K, BsW + i*512);
    }
    __syncthreads();   // compiler drains vmcnt before s_barrier
    #pragma unroll
    for (int ks = 0; ks < 2; ++ks){
      bf16x8 af[4], bfr[4];
      #pragma unroll
      for (int mi = 0; mi < 4; ++mi){
        int r = wm + mi*16 + l15;
        af[mi] = __builtin_bit_cast(bf16x8, *(const uint4*)(As + r*64 + ((ks*32 + quad*8) ^ swr)));
      }
      #pragma unroll
      for (int nj = 0; nj < 4; ++nj){
        int r = wn + nj*16 + l15;
        bfr[nj] = __builtin_bit_cast(bf16x8, *(const uint4*)(Bs + r*64 + ((ks*32 + quad*8) ^ swr)));
      }
      #pragma unroll
      for (int mi = 0; mi < 4; ++mi)
        #pragma unroll
        for (int nj = 0; nj < 4; ++nj)
          acc[mi][nj] = __builtin_amdgcn_mfma_f32_16x16x32_bf16(af[mi], bfr[nj], acc[mi][nj], 0, 0, 0);
    }
    __syncthreads();
  }
  // epilogue: C/D layout col=lane&15, row=quad*4+r
  #pragma unroll
  for (int nj = 0; nj < 4; ++nj){
    int col = bn + wn + nj*16 + l15;
    float bv = bias ? bias[col] : 0.f;
    #pragma unroll
    for (int mi = 0; mi < 4; ++mi){
      #pragma unroll
      for (int r = 0; r < 4; ++r){
        int row = bm + wm + mi*16 + quad*4 + r;
        float v = acc[mi][nj][r] + bv;
        if (act) v = geluf_(v);
        C[(size_t)row*N + col] = fbits(v);
      }
    }
  }
}

// ---------- RoPE: in (B,NN,NHp,64) -> out (B,NHp,NN,64), rotated ----------
__global__ void k_rope(const bf16* __restrict__ in, const float* __restrict__ cw,
                       const float* __restrict__ sw, bf16* __restrict__ out, int NHp, int n){
  int idx = blockIdx.x*256 + threadIdx.x;
  if (idx >= n) return;
  int d2 = idx & 31; int t = idx >> 5;
  int nn = t % NN; t /= NN; int h = t % NHp; int b = t / NHp;
  const bf16* base = in + ((size_t)((b*NN+nn)*NHp + h))*HDIM;
  float e = bf2f(base[2*d2]), o = bf2f(base[2*d2+1]);
  float c = cw[nn*32 + d2], s = sw[nn*32 + d2];
  bf16* ob = out + ((size_t)((b*NHp+h)*NN + nn))*HDIM;
  ob[d2]      = f2bf(e*c - o*s);
  ob[32 + d2] = f2bf(e*s + o*c);
}

// ---------- transpose (B,T,NHp,64) -> (B,NHp,T,64) ----------
__global__ void k_tr(const bf16* __restrict__ in, bf16* __restrict__ out, int T, int NHp, int n){
  int idx = blockIdx.x*256 + threadIdx.x;
  if (idx >= n) return;
  int d = idx & 63; int t = idx >> 6;
  int h = t % NHp; t /= NHp; int tok = t % T; int b = t / T;
  out[((size_t)((b*NHp+h)*T + tok))*64 + d] = in[idx];
}

// ---------- V transpose (B,T,NHp,64) -> (B,NHp,64,T) for MFMA PV B-fragments ----------
__global__ void k_trv(const bf16* __restrict__ in, bf16* __restrict__ out, int T, int NHp, int n){
  int idx = blockIdx.x*256 + threadIdx.x;
  if (idx >= n) return;
  int d = idx & 63; int t = idx >> 6;
  int h = t % NHp; t /= NHp; int tok = t % T; int b = t / T;
  out[((size_t)(b*NHp+h)*64 + d)*T + tok] = in[idx];
}

// ---------- MFMA flash attention ----------
__global__ __launch_bounds__(256) void k_fattn(const ushort* __restrict__ Q, const ushort* __restrict__ K,
                      const ushort* __restrict__ V, ushort* __restrict__ O,
                      int NH, int NKV, int Nq, int Nk, float scale){
  __shared__ ushort Kt[64*72];     // [key][hd]
  __shared__ ushort Vt[64*72];     // [hd][key]
  __shared__ ushort Ps[4][16*72];  // per-wave [q][key]
  int tid = threadIdx.x, lane = tid & 63, wv = tid >> 6;
  int l15 = lane & 15, quad = lane >> 4;
  int nqt = Nq >> 6;
  int qt = blockIdx.x % nqt; int t = blockIdx.x / nqt; int h = t % NH; int b = t / NH;
  int kvh = h / (NH / NKV);
  const ushort* Kb = K + (size_t)(b*NKV+kvh)*Nk*64;
  const ushort* Vb = V + (size_t)(b*NKV+kvh)*64*Nk;
  const ushort* Qp = Q + ((size_t)((b*NH+h)*Nq + qt*64 + wv*16 + l15))*64;
  bf16x8 qf0 = __builtin_bit_cast(bf16x8, *(const uint4*)(Qp + quad*8));
  bf16x8 qf1 = __builtin_bit_cast(bf16x8, *(const uint4*)(Qp + 32 + quad*8));
  f32x4 acc[4] = {};
  float m_run[4] = {-1e30f,-1e30f,-1e30f,-1e30f};
  float l_run[4] = {0.f,0.f,0.f,0.f};
  ushort* Pw = Ps[wv];
  for (int t0 = 0; t0 < Nk; t0 += 64){
    #pragma unroll
    for (int i = 0; i < 2; ++i){
      int c = tid + i*256; int row = c >> 3; int k8 = (c & 7) << 3;
      *(uint4*)(Kt + row*72 + k8) = *(const uint4*)(Kb + (size_t)(t0+row)*64 + k8);
      *(uint4*)(Vt + row*72 + k8) = *(const uint4*)(Vb + (size_t)row*Nk + t0 + k8);
    }
    __syncthreads();
    f32x4 s[4] = {};
    #pragma unroll
    for (int nj = 0; nj < 4; ++nj){
      bf16x8 kf0 = __builtin_bit_cast(bf16x8, *(const uint4*)(Kt + (nj*16+l15)*72 + quad*8));
      s[nj] = __builtin_amdgcn_mfma_f32_16x16x32_bf16(qf0, kf0, s[nj], 0, 0, 0);
      bf16x8 kf1 = __builtin_bit_cast(bf16x8, *(const uint4*)(Kt + (nj*16+l15)*72 + 32 + quad*8));
      s[nj] = __builtin_amdgcn_mfma_f32_16x16x32_bf16(qf1, kf1, s[nj], 0, 0, 0);
    }
    #pragma unroll
    for (int nj = 0; nj < 4; ++nj)
      #pragma unroll
      for (int r = 0; r < 4; ++r) s[nj][r] *= scale;
    float al[4];
    #pragma unroll
    for (int r = 0; r < 4; ++r){
      float tm = fmaxf(fmaxf(s[0][r], s[1][r]), fmaxf(s[2][r], s[3][r]));
      #pragma unroll
      for (int off = 8; off; off >>= 1) tm = fmaxf(tm, __shfl_xor(tm, off, 64));
      float mn = fmaxf(m_run[r], tm);
      al[r] = expf(m_run[r] - mn);
      m_run[r] = mn;
      float ts = 0.f;
      #pragma unroll
      for (int nj = 0; nj < 4; ++nj){ float p = expf(s[nj][r] - mn); s[nj][r] = p; ts += p; }
      #pragma unroll
      for (int off = 8; off; off >>= 1) ts += __shfl_xor(ts, off, 64);
      l_run[r] = l_run[r]*al[r] + ts;
    }
    #pragma unroll
    for (int nj = 0; nj < 4; ++nj){
      #pragma unroll
      for (int r = 0; r < 4; ++r){
        acc[nj][r] *= al[r];
        Pw[(quad*4+r)*72 + nj*16 + l15] = fbits(s[nj][r]);
      }
    }
    bf16x8 pf0 = __builtin_bit_cast(bf16x8, *(const uint4*)(Pw + l15*72 + quad*8));
    bf16x8 pf1 = __builtin_bit_cast(bf16x8, *(const uint4*)(Pw + l15*72 + 32 + quad*8));
    #pragma unroll
    for (int nj = 0; nj < 4; ++nj){
      bf16x8 vf0 = __builtin_bit_cast(bf16x8, *(const uint4*)(Vt + (nj*16+l15)*72 + quad*8));
      acc[nj] = __builtin_amdgcn_mfma_f32_16x16x32_bf16(pf0, vf0, acc[nj], 0, 0, 0);
      bf16x8 vf1 = __builtin_bit_cast(bf16x8, *(const uint4*)(Vt + (nj*16+l15)*72 + 32 + quad*8));
      acc[nj] = __builtin_amdgcn_mfma_f32_16x16x32_bf16(pf1, vf1, acc[nj], 0, 0, 0);
    }
    __syncthreads();
  }
  float inv[4];
  #pragma unroll
  for (int r = 0; r < 4; ++r) inv[r] = 1.f / l_run[r];
  int nbase = qt*64 + wv*16 + quad*4;
  #pragma unroll
  for (int r = 0; r < 4; ++r){
    size_t ob = ((size_t)((b*Nq + nbase + r)*NH + h))*64;
    #pragma unroll
    for (int nj = 0; nj < 4; ++nj)
      O[ob + nj*16 + l15] = fbits(acc[nj][r]*inv[r]);
  }
}

// ---------- residual: X += (mod? g[b,d] : 1) * val ----------
__global__ void k_resid(float* __restrict__ X, const bf16* __restrict__ val,
                        const float* __restrict__ mod, int goff, int n){
  int i = blockIdx.x*256 + threadIdx.x;
  if (i >= n) return;
  float g = 1.f;
  if (mod){ int b = i >> 20; int d = i & 1023; g = mod[b*6144 + goff + d]; }
  X[i] += g*bf2f(val[i]);
}

// ---------- concat [X(fp32), VST(bf16)] -> CAT bf16 ----------
__global__ void k_concat(const float* __restrict__ X, const bf16* __restrict__ V,
                         bf16* __restrict__ C, int n){
  int i = blockIdx.x*256 + threadIdx.x;
  if (i >= n) return;
  int row = i >> 11, col = i & 2047;
  C[i] = (col < 1024) ? f2bf(X[(size_t)row*1024 + col]) : V[(size_t)row*1024 + col - 1024];
}

// ---------- integrator control update ----------
__global__ void k_ctrl(const bf16* __restrict__ ctrl, const float* __restrict__ X,
                       bf16* __restrict__ VST, bf16* __restrict__ XN,
                       const float* __restrict__ mu, int n){
  int i = blockIdx.x*256 + threadIdx.x;
  if (i >= n) return;
  int row = i >> 10, d = i & 1023;
  const bf16* cr = ctrl + (size_t)row*3072;
  float alpha = sigmf_(bf2f(cr[d]));
  float braw  = bf2f(cr[1024 + d]);
  float beta  = fmaxf(braw, 0.f) + log1pf(expf(-fabsf(braw)));
  float gate  = sigmf_(bf2f(cr[2048 + d]));
  float vn = alpha*bf2f(VST[i]) - beta*(X[i] - mu[d]);
  VST[i] = f2bf(vn);
  XN[i]  = f2bf(X[i] + 0.1f*gate*vn);
}

// ---------- hg2: hp = sigmoid(hg1out @ w + b) ; fp32 halt tail ----------
__global__ __launch_bounds__(64) void k_hg2(const bf16* __restrict__ hin, const float* __restrict__ w,
                     const float* __restrict__ bb, float* __restrict__ hp,
                     float* __restrict__ oout, int it){
  int r = blockIdx.x; int lane = threadIdx.x;
  const bf16* hr = hin + (size_t)r*256;
  float s = 0.f;
  #pragma unroll
  for (int i = 0; i < 4; ++i) s += bf2f(hr[lane + i*64])*w[lane + i*64];
  for (int off = 32; off; off >>= 1) s += __shfl_xor(s, off, 64);
  if (lane == 0){
    float v = sigmf_(s + bb[0]);
    hp[r] = v;
    int b = r >> 10, nn = r & 1023;
    oout[((size_t)(b*2 + it) << 10) + nn] = v;
  }
}

// ---------- integ += hp * refined * int_w ----------
__global__ void k_integ(float* __restrict__ X, const float* __restrict__ hp,
                        const bf16* __restrict__ rf, const float* __restrict__ iw, int n){
  int i = blockIdx.x*256 + threadIdx.x;
  if (i >= n) return;
  int row = i >> 10, d = i & 1023;
  X[i] += hp[row]*bf2f(rf[i])*iw[d];
}

extern "C" void kernel_launch(void* const* d_in, const int* in_sizes, int n_in,
                              void* d_out, int out_size, void* d_ws, size_t ws_size,
                              hipStream_t stream) {
  const float* x_in  = (const float*)d_in[0];
  const float* c_in  = (const float*)d_in[1];
  const float* ctx_in= (const float*)d_in[2];
  const float* cosw  = (const float*)d_in[3];
  const float* sinw  = (const float*)d_in[4];
  const float* wq    = (const float*)d_in[5];
  const float* wk    = (const float*)d_in[6];
  const float* wv    = (const float*)d_in[7];
  const float* wo    = (const float*)d_in[8];
  const float* cwq   = (const float*)d_in[9];
  const float* cwk   = (const float*)d_in[10];
  const float* cwv   = (const float*)d_in[11];
  const float* cwo   = (const float*)d_in[12];
  const float* fc1_w = (const float*)d_in[13];
  const float* fc1_b = (const float*)d_in[14];
  const float* fc2_w = (const float*)d_in[15];
  const float* fc2_b = (const float*)d_in[16];
  const float* ada_w = (const float*)d_in[17];
  const float* ada_b = (const float*)d_in[18];
  const float* n1    = (const float*)d_in[19];
  const float* n2    = (const float*)d_in[20];
  const float* n3    = (const float*)d_in[21];
  const float* int_w = (const float*)d_in[22];
  const float* mu    = (const float*)d_in[23];
  const float* hg1_w = (const float*)d_in[24];
  const float* hg1_b = (const float*)d_in[25];
  const float* hg2_w = (const float*)d_in[26];
  const float* hg2_b = (const float*)d_in[27];
  const float* ct1_w = (const float*)d_in[28];
  const float* ct1_b = (const float*)d_in[29];
  const float* ct2_w = (const float*)d_in[30];
  const float* ct2_b = (const float*)d_in[31];
  const float* rf1_w = (const float*)d_in[32];
  const float* rf1_b = (const float*)d_in[33];
  const float* rf2_w = (const float*)d_in[34];
  const float* rf2_b = (const float*)d_in[35];

  float* out_f  = (float*)d_out;
  float* out_hp = out_f + (size_t)BB*NN*DD;

  // ---- workspace map (~112 MB) ----
  char* wsb = (char*)d_ws;
  const size_t Mi = 1u << 20;
  float* X  = (float*)wsb;                    // [0,16MB)
  bf16*  Hh = (bf16*)(wsb + 16*Mi);           // [16,24MB)
  bf16*  Qb = (bf16*)(wsb + 24*Mi);           // [24,32MB)
  bf16*  R  = (bf16*)(wsb + 32*Mi);           // [32,64MB)
  bf16*  QR  = R;
  bf16*  SAb = R + 4*Mi;
  bf16*  KP  = R + 8*Mi;
  bf16*  VP  = R + 9*Mi;
  bf16*  KR  = R + 10*Mi;
  bf16*  VR  = R + 11*Mi;
  bf16*  CTXB= R + 12*Mi;
  bf16*  BIG = R;
  bf16*  CT1 = R + 12*Mi;
  bf16*  HG1 = R + 12*Mi;
  bf16*  RFO = R + 8*Mi;
  float* SIL = (float*)(wsb + 64*Mi);
  float* MOD = SIL + 4096;
  float* HP  = MOD + 24576;
  bf16*  VST = Qb;
  bf16*  XN  = Hh;
  // transposed bf16 weights [N][K] at +65MB (46.5MB)
  bf16* WT   = (bf16*)(wsb + 65*Mi);
  bf16* wqT  = WT;                 // 1024x1024
  bf16* wkT  = wqT  + 1048576;     // 256x1024
  bf16* wvT  = wkT  + 262144;      // 256x1024
  bf16* woT  = wvT  + 262144;      // 1024x1024
  bf16* cwqT = woT  + 1048576;     // 1024x1024
  bf16* cwkT = cwqT + 1048576;     // 1024x2048
  bf16* cwvT = cwkT + 2097152;     // 1024x2048
  bf16* cwoT = cwvT + 2097152;     // 1024x1024
  bf16* fc1T = cwoT + 1048576;     // 4096x1024
  bf16* fc2T = fc1T + 4194304;     // 1024x4096
  bf16* ct1T = fc2T + 4194304;     // 512x2048
  bf16* ct2T = ct1T + 1048576;     // 3072x512
  bf16* rf1T = ct2T + 1572864;     // 2048x1024
  bf16* rf2T = rf1T + 2097152;     // 1024x2048
  bf16* hg1T = rf2T + 2097152;     // 256x1024

  const int NT = BB*NN*DD;
  const float scale = 0.125f;
  #define G1(n) dim3(((n)+255)/256), dim3(256)
  #define WTR(src,dst,K,N) k_wt<<<dim3((N)/64,(K)/64), dim3(256), 0, stream>>>((src),(dst),(K),(N))
  #define MM(Aptr,BTptr,biasptr,Cptr,M,N,K,act) \
    k_mm2<<<dim3((N)/128,(M)/128), dim3(256), 0, stream>>>((const ushort*)(Aptr),(const ushort*)(BTptr),(biasptr),(ushort*)(Cptr),(M),(N),(K),(act))

  // ---- weight prep: fp32 [K][N] -> bf16 [N][K] ----
  WTR(wq,   wqT, 1024, 1024);
  WTR(wk,   wkT, 1024, 256);
  WTR(wv,   wvT, 1024, 256);
  WTR(wo,   woT, 1024, 1024);
  WTR(cwq,  cwqT,1024, 1024);
  WTR(cwk,  cwkT,2048, 1024);
  WTR(cwv,  cwvT,2048, 1024);
  WTR(cwo,  cwoT,1024, 1024);
  WTR(fc1_w,fc1T,1024, 4096);
  WTR(fc2_w,fc2T,4096, 1024);
  WTR(ct1_w,ct1T,2048, 512);
  WTR(ct2_w,ct2T,512,  3072);
  WTR(rf1_w,rf1T,1024, 2048);
  WTR(rf2_w,rf2T,2048, 1024);
  WTR(hg1_w,hg1T,1024, 256);

  // x -> X; mod = silu(c) @ ada_w + ada_b (K-split atomic GEMV)
  k_copy4<<<G1(NT/4), 0, stream>>>((const float4*)x_in, (float4*)X, NT/4);
  k_silu<<<G1(BB*DD), 0, stream>>>(c_in, SIL, BB*DD);
  k_adab<<<G1(BB*6144), 0, stream>>>(ada_b, MOD, BB*6144);
  k_ada2<<<dim3(6,32), dim3(256), 0, stream>>>(SIL, ada_w, MOD);

  // ---- self-attention ----
  k_rms<<<dim3(4096), dim3(256), 0, stream>>>(X, n1, MOD, DD, 0, Hh, 1);
  MM(Hh, wqT, nullptr, Qb, 4096, 1024, 1024, 0);
  MM(Hh, wkT, nullptr, KP, 4096, 256, 1024, 0);
  MM(Hh, wvT, nullptr, VP, 4096, 256, 1024, 0);
  k_rope<<<G1(BB*HH*NN*32), 0, stream>>>(Qb, cosw, sinw, QR, HH, BB*HH*NN*32);
  k_rope<<<G1(BB*KVH*NN*32), 0, stream>>>(KP, cosw, sinw, KR, KVH, BB*KVH*NN*32);
  k_trv<<<G1(BB*NN*KVH*64), 0, stream>>>(VP, VR, NN, KVH, BB*NN*KVH*64);
  k_fattn<<<dim3(BB*HH*(NN/64)), dim3(256), 0, stream>>>((const ushort*)QR, (const ushort*)KR,
      (const ushort*)VR, (ushort*)SAb, HH, KVH, NN, NN, scale);
  MM(SAb, woT, nullptr, Hh, 4096, 1024, 1024, 0);
  k_resid<<<G1(NT), 0, stream>>>(X, Hh, MOD, 2*DD, NT);

  // ---- cross-attention ----
  k_rms<<<dim3(4096), dim3(256), 0, stream>>>(X, n2, nullptr, 0, 0, Hh, 0);
  MM(Hh, cwqT, nullptr, Qb, 4096, 1024, 1024, 0);
  k_tr<<<G1(NT), 0, stream>>>(Qb, QR, NN, HH, NT);
  k_f2bfv<<<G1(BB*SS*CTXD), 0, stream>>>(ctx_in, CTXB, BB*SS*CTXD);
  MM(CTXB, cwkT, nullptr, KP, 512, 1024, 2048, 0);
  MM(CTXB, cwvT, nullptr, VP, 512, 1024, 2048, 0);
  k_tr<<<G1(BB*SS*HH*64), 0, stream>>>(KP, KR, SS, HH, BB*SS*HH*64);
  k_trv<<<G1(BB*SS*HH*64), 0, stream>>>(VP, VR, SS, HH, BB*SS*HH*64);
  k_fattn<<<dim3(BB*HH*(NN/64)), dim3(256), 0, stream>>>((const ushort*)QR, (const ushort*)KR,
      (const ushort*)VR, (ushort*)SAb, HH, HH, NN, SS, scale);
  MM(SAb, cwoT, nullptr, Hh, 4096, 1024, 1024, 0);
  k_resid<<<G1(NT), 0, stream>>>(X, Hh, nullptr, 0, NT);

  // ---- MLP ----
  k_rms<<<dim3(4096), dim3(256), 0, stream>>>(X, n3, MOD, 4*DD, 3*DD, Hh, 1);
  MM(Hh, fc1T, fc1_b, BIG, 4096, 4096, 1024, 1);
  MM(BIG, fc2T, fc2_b, Qb, 4096, 1024, 4096, 0);
  k_resid<<<G1(NT), 0, stream>>>(X, Qb, MOD, 5*DD, NT);

  // ---- integrator (NITER=2) ----
  k_zero16<<<G1(NT), 0, stream>>>((unsigned short*)VST, NT);
  for (int it = 0; it < 2; ++it){
    k_concat<<<G1(2*NT), 0, stream>>>(X, VST, BIG, 2*NT);
    MM(BIG, ct1T, ct1_b, CT1, 4096, 512, 2048, 1);
    MM(CT1, ct2T, ct2_b, BIG, 4096, 3072, 512, 0);
    k_ctrl<<<G1(NT), 0, stream>>>(BIG, X, VST, XN, mu, NT);
    MM(XN, hg1T, hg1_b, HG1, 4096, 256, 1024, 1);
    k_hg2<<<dim3(4096), dim3(64), 0, stream>>>(HG1, hg2_w, hg2_b, HP, out_hp, it);
    MM(XN, rf1T, rf1_b, BIG, 4096, 2048, 1024, 1);
    MM(BIG, rf2T, rf2_b, RFO, 4096, 1024, 2048, 0);
    k_integ<<<G1(NT), 0, stream>>>(X, HP, RFO, int_w, NT);
  }
  // ---- final output: FP32 ----
  k_copy4<<<G1(NT/4), 0, stream>>>((const float4*)X, (float4*)out_f, NT/4);
  #undef G1
  #undef WTR
  #undef MM
}

// Round 5
// 1124.728 us; speedup vs baseline: 2.2398x; 1.0416x over previous
//
#include <hip/hip_runtime.h>
#include <hip/hip_bf16.h>
#include <math.h>

typedef __hip_bfloat16 bf16;
typedef unsigned short ushort;
typedef __bf16 bf16x8 __attribute__((ext_vector_type(8)));
typedef unsigned short u16x8 __attribute__((ext_vector_type(8)));
typedef float f32x4 __attribute__((ext_vector_type(4)));

#define BB 4
#define NN 1024
#define DD 1024
#define HH 16
#define KVH 4
#define HDIM 64
#define SS 128
#define CTXD 2048
#define MLPDIM 4096

__device__ __forceinline__ float bf2f(bf16 v){ return __bfloat162float(v); }
__device__ __forceinline__ bf16 f2bf(float v){ return __float2bfloat16(v); }
__device__ __forceinline__ ushort fbits(float v){ bf16 h = __float2bfloat16(v); return *(ushort*)&h; }
__device__ __forceinline__ float ubf(ushort u){ unsigned int x = ((unsigned int)u) << 16; float f; *(unsigned int*)&f = x; return f; }
__device__ __forceinline__ float sigmf_(float x){ return 1.f/(1.f+expf(-x)); }
__device__ __forceinline__ float geluf_(float x){ return 0.5f*x*(1.f+erff(x*0.70710678118f)); }

// async global->LDS, 16B per lane; LDS dest = base + lane*16 (wave-uniform base)
typedef const __attribute__((address_space(1))) void* gas_t;
typedef __attribute__((address_space(3))) void* las_t;
__device__ __forceinline__ void gl2lds16(const void* g, void* l){
  __builtin_amdgcn_global_load_lds((gas_t)g, (las_t)l, 16, 0, 0);
}

// ---------- converts ----------
__global__ void k_copy4(const float4* __restrict__ in, float4* __restrict__ out, int n4){
  int i = blockIdx.x*256 + threadIdx.x;
  if (i < n4) out[i] = in[i];
}
__global__ void k_f2bfv(const float* __restrict__ in, bf16* __restrict__ out, int n){
  int i = blockIdx.x*256 + threadIdx.x;
  if (i < n) out[i] = f2bf(in[i]);
}
__global__ void k_silu(const float* __restrict__ c, float* __restrict__ out, int n){
  int i = blockIdx.x*256 + threadIdx.x;
  if (i < n){ float v = c[i]; out[i] = v*sigmf_(v); }
}
__global__ void k_zero16(unsigned short* __restrict__ p, int n){
  int i = blockIdx.x*256 + threadIdx.x;
  if (i < n) p[i] = 0;
}

// ---------- weight transpose+convert: in fp32 [K][N] -> out bf16 [N][K] ----------
__global__ __launch_bounds__(256) void k_wt(const float* __restrict__ in, bf16* __restrict__ out, int K, int N){
  __shared__ float t[64][65];
  int bn = blockIdx.x*64, bk = blockIdx.y*64;
  int tid = threadIdx.x;
  int c4 = (tid & 15)*4, r = tid >> 4;
  #pragma unroll
  for (int i = 0; i < 4; ++i){
    float4 v = *(const float4*)(in + (size_t)(bk + r + i*16)*N + bn + c4);
    t[c4+0][r+i*16] = v.x; t[c4+1][r+i*16] = v.y; t[c4+2][r+i*16] = v.z; t[c4+3][r+i*16] = v.w;
  }
  __syncthreads();
  int n = tid >> 2, k16 = (tid & 3)*16;
  bf16* orow = out + (size_t)(bn + n)*K + bk + k16;
  #pragma unroll
  for (int j = 0; j < 16; ++j) orow[j] = f2bf(t[n][k16 + j]);
}

// ---------- adaLN: mod = silu(c) @ ada_w + ada_b ----------
__global__ void k_adab(const float* __restrict__ b, float* __restrict__ mod, int n){
  int idx = blockIdx.x*256 + threadIdx.x;
  if (idx < n) mod[idx] = b[idx % 6144];
}
__global__ __launch_bounds__(256) void k_ada2(const float* __restrict__ sc, const float* __restrict__ w,
                       float* __restrict__ mod){
  __shared__ float sl[4][32];
  int tid = threadIdx.x;
  int col4 = blockIdx.x*1024 + tid*4;
  int k0 = blockIdx.y*32;
  if (tid < 128) sl[tid >> 5][tid & 31] = sc[(tid >> 5)*DD + k0 + (tid & 31)];
  __syncthreads();
  f32x4 acc[4] = {};
  for (int kk = 0; kk < 32; ++kk){
    const float4 wv4 = *(const float4*)(w + (size_t)(k0 + kk)*6144 + col4);
    #pragma unroll
    for (int b = 0; b < 4; ++b){
      float s = sl[b][kk];
      acc[b][0] += s*wv4.x; acc[b][1] += s*wv4.y; acc[b][2] += s*wv4.z; acc[b][3] += s*wv4.w;
    }
  }
  #pragma unroll
  for (int b = 0; b < 4; ++b)
    #pragma unroll
    for (int j = 0; j < 4; ++j)
      atomicAdd(&mod[(size_t)b*6144 + col4 + j], acc[b][j]);
}

// ---------- RMSNorm (+optional adaLN scale/shift) ----------
__global__ __launch_bounds__(256) void k_rms(const float* __restrict__ X, const float* __restrict__ w,
                      const float* __restrict__ mod, int sc_off, int sh_off,
                      bf16* __restrict__ out, int use_mod){
  __shared__ float red[256];
  int row = blockIdx.x;
  int b = row >> 10;
  int tid = threadIdx.x;
  const float* xr = X + (size_t)row*DD;
  float s = 0.f;
  #pragma unroll
  for (int i = 0; i < 4; ++i){ float v = xr[tid + i*256]; s += v*v; }
  red[tid] = s; __syncthreads();
  for (int st = 128; st > 0; st >>= 1){ if (tid < st) red[tid] += red[tid+st]; __syncthreads(); }
  float rstd = rsqrtf(red[0]*(1.f/DD) + 1e-6f);
  bf16* orow = out + (size_t)row*DD;
  const float* mrow = use_mod ? (mod + (size_t)b*6*DD) : nullptr;
  #pragma unroll
  for (int i = 0; i < 4; ++i){
    int d = tid + i*256;
    float v = xr[d]*rstd*w[d];
    if (use_mod) v = v*(1.f + mrow[sc_off + d]) + mrow[sh_off + d];
    orow[d] = f2bf(v);
  }
}

// ---------- MFMA GEMM v2: C(MxN,bf16) = A(MxK,bf16) @ BT(NxK,bf16)^T [+bias][gelu] ----------
// 128x128 tile, BK=64, gl2lds staging, XOR-swizzled LDS (T2 + rule 21).
__global__ __launch_bounds__(256,2) void k_mm2(const ushort* __restrict__ A, const ushort* __restrict__ BT,
                      const float* __restrict__ bias, ushort* __restrict__ C,
                      int M, int N, int K, int act){
  __shared__ ushort As[128*64];   // phys [row][kphys]; logical k-slot t at phys slot t^(row&7)
  __shared__ ushort Bs[128*64];
  int tid = threadIdx.x, lane = tid & 63, wv = tid >> 6;
  int l15 = lane & 15, quad = lane >> 4;
  int bm = blockIdx.y*128, bn = blockIdx.x*128;
  int wm = (wv & 1)*64, wn = (wv >> 1)*64;
  int lr = lane >> 3, lc = lane & 7;
  int ksw = (lc ^ lr) << 3;
  f32x4 acc[4][4] = {};
  const ushort* Abase = A  + (size_t)(bm + wv*32 + lr)*K + ksw;
  const ushort* Bbase = BT + (size_t)(bn + wv*32 + lr)*K + ksw;
  ushort* AsW = As + wv*2048;
  ushort* BsW = Bs + wv*2048;
  int swr = (l15 & 7) << 3;
  for (int k0 = 0; k0 < K; k0 += 64){
    #pragma unroll
    for (int i = 0; i < 4; ++i){
      gl2lds16(Abase + k0 + (size_t)(i*8)*K, AsW + i*512);
      gl2lds16(Bbase + k0 + (size_t)(i*8)*K, BsW + i*512);
    }
    __syncthreads();
    #pragma unroll
    for (int ks = 0; ks < 2; ++ks){
      bf16x8 af[4], bfr[4];
      #pragma unroll
      for (int mi = 0; mi < 4; ++mi){
        int r = wm + mi*16 + l15;
        af[mi] = __builtin_bit_cast(bf16x8, *(const uint4*)(As + r*64 + ((ks*32 + quad*8) ^ swr)));
      }
      #pragma unroll
      for (int nj = 0; nj < 4; ++nj){
        int r = wn + nj*16 + l15;
        bfr[nj] = __builtin_bit_cast(bf16x8, *(const uint4*)(Bs + r*64 + ((ks*32 + quad*8) ^ swr)));
      }
      #pragma unroll
      for (int mi = 0; mi < 4; ++mi)
        #pragma unroll
        for (int nj = 0; nj < 4; ++nj)
          acc[mi][nj] = __builtin_amdgcn_mfma_f32_16x16x32_bf16(af[mi], bfr[nj], acc[mi][nj], 0, 0, 0);
    }
    __syncthreads();
  }
  #pragma unroll
  for (int nj = 0; nj < 4; ++nj){
    int col = bn + wn + nj*16 + l15;
    float bv = bias ? bias[col] : 0.f;
    #pragma unroll
    for (int mi = 0; mi < 4; ++mi){
      #pragma unroll
      for (int r = 0; r < 4; ++r){
        int row = bm + wm + mi*16 + quad*4 + r;
        float v = acc[mi][nj][r] + bv;
        if (act) v = geluf_(v);
        C[(size_t)row*N + col] = fbits(v);
      }
    }
  }
}

// ---------- MFMA GEMM half-width: BM=128, BN=64 — for grid-starved (skinny) GEMMs ----------
// 4 waves, wave wv owns rows wv*32..wv*32+31 x all 64 cols (acc 2x4).
__global__ __launch_bounds__(256,2) void k_mm2h(const ushort* __restrict__ A, const ushort* __restrict__ BT,
                      const float* __restrict__ bias, ushort* __restrict__ C,
                      int M, int N, int K, int act){
  __shared__ ushort As[128*64];
  __shared__ ushort Bs[64*64];
  int tid = threadIdx.x, lane = tid & 63, wv = tid >> 6;
  int l15 = lane & 15, quad = lane >> 4;
  int bm = blockIdx.y*128, bn = blockIdx.x*64;
  int wm = wv*32;
  int lr = lane >> 3, lc = lane & 7;
  int ksw = (lc ^ lr) << 3;
  f32x4 acc[2][4] = {};
  const ushort* Abase = A  + (size_t)(bm + wv*32 + lr)*K + ksw;
  const ushort* Bbase = BT + (size_t)(bn + wv*16 + lr)*K + ksw;
  ushort* AsW = As + wv*2048;
  ushort* BsW = Bs + wv*1024;
  int swr = (l15 & 7) << 3;
  for (int k0 = 0; k0 < K; k0 += 64){
    #pragma unroll
    for (int i = 0; i < 4; ++i)
      gl2lds16(Abase + k0 + (size_t)(i*8)*K, AsW + i*512);
    #pragma unroll
    for (int i = 0; i < 2; ++i)
      gl2lds16(Bbase + k0 + (size_t)(i*8)*K, BsW + i*512);
    __syncthreads();
    #pragma unroll
    for (int ks = 0; ks < 2; ++ks){
      bf16x8 af[2], bfr[4];
      #pragma unroll
      for (int mi = 0; mi < 2; ++mi){
        int r = wm + mi*16 + l15;
        af[mi] = __builtin_bit_cast(bf16x8, *(const uint4*)(As + r*64 + ((ks*32 + quad*8) ^ swr)));
      }
      #pragma unroll
      for (int nj = 0; nj < 4; ++nj){
        int r = nj*16 + l15;
        bfr[nj] = __builtin_bit_cast(bf16x8, *(const uint4*)(Bs + r*64 + ((ks*32 + quad*8) ^ swr)));
      }
      #pragma unroll
      for (int mi = 0; mi < 2; ++mi)
        #pragma unroll
        for (int nj = 0; nj < 4; ++nj)
          acc[mi][nj] = __builtin_amdgcn_mfma_f32_16x16x32_bf16(af[mi], bfr[nj], acc[mi][nj], 0, 0, 0);
    }
    __syncthreads();
  }
  #pragma unroll
  for (int nj = 0; nj < 4; ++nj){
    int col = bn + nj*16 + l15;
    float bv = bias ? bias[col] : 0.f;
    #pragma unroll
    for (int mi = 0; mi < 2; ++mi){
      #pragma unroll
      for (int r = 0; r < 4; ++r){
        int row = bm + wm + mi*16 + quad*4 + r;
        float v = acc[mi][nj][r] + bv;
        if (act) v = geluf_(v);
        C[(size_t)row*N + col] = fbits(v);
      }
    }
  }
}

// ---------- RoPE: in (B,NN,NHp,64) -> out (B,NHp,NN,64), rotated ----------
__global__ void k_rope(const bf16* __restrict__ in, const float* __restrict__ cw,
                       const float* __restrict__ sw, bf16* __restrict__ out, int NHp, int n){
  int idx = blockIdx.x*256 + threadIdx.x;
  if (idx >= n) return;
  int d2 = idx & 31; int t = idx >> 5;
  int nn = t % NN; t /= NN; int h = t % NHp; int b = t / NHp;
  const bf16* base = in + ((size_t)((b*NN+nn)*NHp + h))*HDIM;
  float e = bf2f(base[2*d2]), o = bf2f(base[2*d2+1]);
  float c = cw[nn*32 + d2], s = sw[nn*32 + d2];
  bf16* ob = out + ((size_t)((b*NHp+h)*NN + nn))*HDIM;
  ob[d2]      = f2bf(e*c - o*s);
  ob[32 + d2] = f2bf(e*s + o*c);
}

// ---------- transpose (B,T,NHp,64) -> (B,NHp,T,64) ----------
__global__ void k_tr(const bf16* __restrict__ in, bf16* __restrict__ out, int T, int NHp, int n){
  int idx = blockIdx.x*256 + threadIdx.x;
  if (idx >= n) return;
  int d = idx & 63; int t = idx >> 6;
  int h = t % NHp; t /= NHp; int tok = t % T; int b = t / T;
  out[((size_t)((b*NHp+h)*T + tok))*64 + d] = in[idx];
}

// ---------- V transpose (B,T,NHp,64) -> (B,NHp,64,T) ----------
__global__ void k_trv(const bf16* __restrict__ in, bf16* __restrict__ out, int T, int NHp, int n){
  int idx = blockIdx.x*256 + threadIdx.x;
  if (idx >= n) return;
  int d = idx & 63; int t = idx >> 6;
  int h = t % NHp; t /= NHp; int tok = t % T; int b = t / T;
  out[((size_t)(b*NHp+h)*64 + d)*T + tok] = in[idx];
}

// ---------- MFMA flash attention (gl2lds staging + XOR-swizzled LDS, T2/rule21) ----------
// K tile: Kt[key][slot] linear phys, logical slot t at phys t^(key&7). Same for V [hd][keyslot].
// Scale folded into Q fragment. setprio(1) around MFMA clusters (T5).
__global__ __launch_bounds__(256) void k_fattn(const ushort* __restrict__ Q, const ushort* __restrict__ K,
                      const ushort* __restrict__ V, ushort* __restrict__ O,
                      int NH, int NKV, int Nq, int Nk, float scale){
  __shared__ ushort Kt[64*64];
  __shared__ ushort Vt[64*64];
  __shared__ ushort Ps[4][16*72];  // per-wave [q][key], stride 72
  int tid = threadIdx.x, lane = tid & 63, wv = tid >> 6;
  int l15 = lane & 15, quad = lane >> 4;
  int lr = lane >> 3, lc = lane & 7;
  int ksw = (lc ^ lr) << 3;
  int swr = (l15 & 7) << 3;
  int nqt = Nq >> 6;
  int qt = blockIdx.x % nqt; int t = blockIdx.x / nqt; int h = t % NH; int b = t / NH;
  int kvh = h / (NH / NKV);
  const ushort* Kb = K + (size_t)(b*NKV+kvh)*Nk*64 + ksw;   // +row*64 per call
  const ushort* Vb = V + (size_t)(b*NKV+kvh)*64*Nk + ksw;   // +row*Nk per call
  const ushort* Qp = Q + ((size_t)((b*NH+h)*Nq + qt*64 + wv*16 + l15))*64;
  // load Q fragments and fold in softmax scale (exact: 0.125 = 2^-3)
  uint4 qraw0 = *(const uint4*)(Qp + quad*8);
  uint4 qraw1 = *(const uint4*)(Qp + 32 + quad*8);
  u16x8 q0 = __builtin_bit_cast(u16x8, qraw0), q1 = __builtin_bit_cast(u16x8, qraw1);
  #pragma unroll
  for (int j = 0; j < 8; ++j){ q0[j] = fbits(ubf(q0[j])*scale); q1[j] = fbits(ubf(q1[j])*scale); }
  bf16x8 qf0 = __builtin_bit_cast(bf16x8, q0);
  bf16x8 qf1 = __builtin_bit_cast(bf16x8, q1);
  f32x4 acc[4] = {};
  float m_run[4] = {-1e30f,-1e30f,-1e30f,-1e30f};
  float l_run[4] = {0.f,0.f,0.f,0.f};
  ushort* Pw = Ps[wv];
  int wrow = wv*16;   // this wave stages rows wrow..wrow+15 (two 8-row chunks)
  for (int t0 = 0; t0 < Nk; t0 += 64){
    #pragma unroll
    for (int i = 0; i < 2; ++i){
      int row = wrow + i*8 + lr;
      gl2lds16(Kb + (size_t)(t0+row)*64, Kt + (wrow + i*8)*64);
      gl2lds16(Vb + (size_t)row*Nk + t0, Vt + (wrow + i*8)*64);
    }
    __syncthreads();
    // S = Q @ K^T
    f32x4 s[4] = {};
    __builtin_amdgcn_s_setprio(1);
    #pragma unroll
    for (int nj = 0; nj < 4; ++nj){
      const ushort* kr = Kt + (nj*16+l15)*64;
      bf16x8 kf0 = __builtin_bit_cast(bf16x8, *(const uint4*)(kr + ((quad*8) ^ swr)));
      s[nj] = __builtin_amdgcn_mfma_f32_16x16x32_bf16(qf0, kf0, s[nj], 0, 0, 0);
      bf16x8 kf1 = __builtin_bit_cast(bf16x8, *(const uint4*)(kr + ((32 + quad*8) ^ swr)));
      s[nj] = __builtin_amdgcn_mfma_f32_16x16x32_bf16(qf1, kf1, s[nj], 0, 0, 0);
    }
    __builtin_amdgcn_s_setprio(0);
    // online softmax; row = quad*4+r
    float al[4];
    #pragma unroll
    for (int r = 0; r < 4; ++r){
      float tm = fmaxf(fmaxf(s[0][r], s[1][r]), fmaxf(s[2][r], s[3][r]));
      #pragma unroll
      for (int off = 8; off; off >>= 1) tm = fmaxf(tm, __shfl_xor(tm, off, 64));
      float mn = fmaxf(m_run[r], tm);
      al[r] = expf(m_run[r] - mn);
      m_run[r] = mn;
      float ts = 0.f;
      #pragma unroll
      for (int nj = 0; nj < 4; ++nj){ float p = expf(s[nj][r] - mn); s[nj][r] = p; ts += p; }
      #pragma unroll
      for (int off = 8; off; off >>= 1) ts += __shfl_xor(ts, off, 64);
      l_run[r] = l_run[r]*al[r] + ts;
    }
    #pragma unroll
    for (int nj = 0; nj < 4; ++nj){
      #pragma unroll
      for (int r = 0; r < 4; ++r){
        acc[nj][r] *= al[r];
        Pw[(quad*4+r)*72 + nj*16 + l15] = fbits(s[nj][r]);
      }
    }
    // O += P @ V  (P in wave-private LDS; same-wave ordering, no barrier)
    bf16x8 pf0 = __builtin_bit_cast(bf16x8, *(const uint4*)(Pw + l15*72 + quad*8));
    bf16x8 pf1 = __builtin_bit_cast(bf16x8, *(const uint4*)(Pw + l15*72 + 32 + quad*8));
    __builtin_amdgcn_s_setprio(1);
    #pragma unroll
    for (int nj = 0; nj < 4; ++nj){
      const ushort* vr = Vt + (nj*16+l15)*64;
      bf16x8 vf0 = __builtin_bit_cast(bf16x8, *(const uint4*)(vr + ((quad*8) ^ swr)));
      acc[nj] = __builtin_amdgcn_mfma_f32_16x16x32_bf16(pf0, vf0, acc[nj], 0, 0, 0);
      bf16x8 vf1 = __builtin_bit_cast(bf16x8, *(const uint4*)(vr + ((32 + quad*8) ^ swr)));
      acc[nj] = __builtin_amdgcn_mfma_f32_16x16x32_bf16(pf1, vf1, acc[nj], 0, 0, 0);
    }
    __builtin_amdgcn_s_setprio(0);
    __syncthreads();
  }
  float inv[4];
  #pragma unroll
  for (int r = 0; r < 4; ++r) inv[r] = 1.f / l_run[r];
  int nbase = qt*64 + wv*16 + quad*4;
  #pragma unroll
  for (int r = 0; r < 4; ++r){
    size_t ob = ((size_t)((b*Nq + nbase + r)*NH + h))*64;
    #pragma unroll
    for (int nj = 0; nj < 4; ++nj)
      O[ob + nj*16 + l15] = fbits(acc[nj][r]*inv[r]);
  }
}

// ---------- residual: X += (mod? g[b,d] : 1) * val ----------
__global__ void k_resid(float* __restrict__ X, const bf16* __restrict__ val,
                        const float* __restrict__ mod, int goff, int n){
  int i = blockIdx.x*256 + threadIdx.x;
  if (i >= n) return;
  float g = 1.f;
  if (mod){ int b = i >> 20; int d = i & 1023; g = mod[b*6144 + goff + d]; }
  X[i] += g*bf2f(val[i]);
}

// ---------- concat [X(fp32), VST(bf16)] -> CAT bf16 ----------
__global__ void k_concat(const float* __restrict__ X, const bf16* __restrict__ V,
                         bf16* __restrict__ C, int n){
  int i = blockIdx.x*256 + threadIdx.x;
  if (i >= n) return;
  int row = i >> 11, col = i & 2047;
  C[i] = (col < 1024) ? f2bf(X[(size_t)row*1024 + col]) : V[(size_t)row*1024 + col - 1024];
}

// ---------- integrator control update ----------
__global__ void k_ctrl(const bf16* __restrict__ ctrl, const float* __restrict__ X,
                       bf16* __restrict__ VST, bf16* __restrict__ XN,
                       const float* __restrict__ mu, int n){
  int i = blockIdx.x*256 + threadIdx.x;
  if (i >= n) return;
  int row = i >> 10, d = i & 1023;
  const bf16* cr = ctrl + (size_t)row*3072;
  float alpha = sigmf_(bf2f(cr[d]));
  float braw  = bf2f(cr[1024 + d]);
  float beta  = fmaxf(braw, 0.f) + log1pf(expf(-fabsf(braw)));
  float gate  = sigmf_(bf2f(cr[2048 + d]));
  float vn = alpha*bf2f(VST[i]) - beta*(X[i] - mu[d]);
  VST[i] = f2bf(vn);
  XN[i]  = f2bf(X[i] + 0.1f*gate*vn);
}

// ---------- hg2: hp = sigmoid(hg1out @ w + b) ; fp32 halt tail ----------
__global__ __launch_bounds__(64) void k_hg2(const bf16* __restrict__ hin, const float* __restrict__ w,
                     const float* __restrict__ bb, float* __restrict__ hp,
                     float* __restrict__ oout, int it){
  int r = blockIdx.x; int lane = threadIdx.x;
  const bf16* hr = hin + (size_t)r*256;
  float s = 0.f;
  #pragma unroll
  for (int i = 0; i < 4; ++i) s += bf2f(hr[lane + i*64])*w[lane + i*64];
  for (int off = 32; off; off >>= 1) s += __shfl_xor(s, off, 64);
  if (lane == 0){
    float v = sigmf_(s + bb[0]);
    hp[r] = v;
    int b = r >> 10, nn = r & 1023;
    oout[((size_t)(b*2 + it) << 10) + nn] = v;
  }
}

// ---------- integ += hp * refined * int_w ----------
__global__ void k_integ(float* __restrict__ X, const float* __restrict__ hp,
                        const bf16* __restrict__ rf, const float* __restrict__ iw, int n){
  int i = blockIdx.x*256 + threadIdx.x;
  if (i >= n) return;
  int row = i >> 10, d = i & 1023;
  X[i] += hp[row]*bf2f(rf[i])*iw[d];
}

extern "C" void kernel_launch(void* const* d_in, const int* in_sizes, int n_in,
                              void* d_out, int out_size, void* d_ws, size_t ws_size,
                              hipStream_t stream) {
  const float* x_in  = (const float*)d_in[0];
  const float* c_in  = (const float*)d_in[1];
  const float* ctx_in= (const float*)d_in[2];
  const float* cosw  = (const float*)d_in[3];
  const float* sinw  = (const float*)d_in[4];
  const float* wq    = (const float*)d_in[5];
  const float* wk    = (const float*)d_in[6];
  const float* wv    = (const float*)d_in[7];
  const float* wo    = (const float*)d_in[8];
  const float* cwq   = (const float*)d_in[9];
  const float* cwk   = (const float*)d_in[10];
  const float* cwv   = (const float*)d_in[11];
  const float* cwo   = (const float*)d_in[12];
  const float* fc1_w = (const float*)d_in[13];
  const float* fc1_b = (const float*)d_in[14];
  const float* fc2_w = (const float*)d_in[15];
  const float* fc2_b = (const float*)d_in[16];
  const float* ada_w = (const float*)d_in[17];
  const float* ada_b = (const float*)d_in[18];
  const float* n1    = (const float*)d_in[19];
  const float* n2    = (const float*)d_in[20];
  const float* n3    = (const float*)d_in[21];
  const float* int_w = (const float*)d_in[22];
  const float* mu    = (const float*)d_in[23];
  const float* hg1_w = (const float*)d_in[24];
  const float* hg1_b = (const float*)d_in[25];
  const float* hg2_w = (const float*)d_in[26];
  const float* hg2_b = (const float*)d_in[27];
  const float* ct1_w = (const float*)d_in[28];
  const float* ct1_b = (const float*)d_in[29];
  const float* ct2_w = (const float*)d_in[30];
  const float* ct2_b = (const float*)d_in[31];
  const float* rf1_w = (const float*)d_in[32];
  const float* rf1_b = (const float*)d_in[33];
  const float* rf2_w = (const float*)d_in[34];
  const float* rf2_b = (const float*)d_in[35];

  float* out_f  = (float*)d_out;
  float* out_hp = out_f + (size_t)BB*NN*DD;

  // ---- workspace map (~112 MB) ----
  char* wsb = (char*)d_ws;
  const size_t Mi = 1u << 20;
  float* X  = (float*)wsb;                    // [0,16MB)
  bf16*  Hh = (bf16*)(wsb + 16*Mi);           // [16,24MB)
  bf16*  Qb = (bf16*)(wsb + 24*Mi);           // [24,32MB)
  bf16*  R  = (bf16*)(wsb + 32*Mi);           // [32,64MB)
  bf16*  QR  = R;
  bf16*  SAb = R + 4*Mi;
  bf16*  KP  = R + 8*Mi;
  bf16*  VP  = R + 9*Mi;
  bf16*  KR  = R + 10*Mi;
  bf16*  VR  = R + 11*Mi;
  bf16*  CTXB= R + 12*Mi;
  bf16*  BIG = R;
  bf16*  CT1 = R + 12*Mi;
  bf16*  HG1 = R + 12*Mi;
  bf16*  RFO = R + 8*Mi;
  float* SIL = (float*)(wsb + 64*Mi);
  float* MOD = SIL + 4096;
  float* HP  = MOD + 24576;
  bf16*  VST = Qb;
  bf16*  XN  = Hh;
  // transposed bf16 weights [N][K] at +65MB (46.5MB)
  bf16* WT   = (bf16*)(wsb + 65*Mi);
  bf16* wqT  = WT;                 // 1024x1024
  bf16* wkT  = wqT  + 1048576;     // 256x1024
  bf16* wvT  = wkT  + 262144;      // 256x1024
  bf16* woT  = wvT  + 262144;      // 1024x1024
  bf16* cwqT = woT  + 1048576;     // 1024x1024
  bf16* cwkT = cwqT + 1048576;     // 1024x2048
  bf16* cwvT = cwkT + 2097152;     // 1024x2048
  bf16* cwoT = cwvT + 2097152;     // 1024x1024
  bf16* fc1T = cwoT + 1048576;     // 4096x1024
  bf16* fc2T = fc1T + 4194304;     // 1024x4096
  bf16* ct1T = fc2T + 4194304;     // 512x2048
  bf16* ct2T = ct1T + 1048576;     // 3072x512
  bf16* rf1T = ct2T + 1572864;     // 2048x1024
  bf16* rf2T = rf1T + 2097152;     // 1024x2048
  bf16* hg1T = rf2T + 2097152;     // 256x1024

  const int NT = BB*NN*DD;
  const float scale = 0.125f;
  #define G1(n) dim3(((n)+255)/256), dim3(256)
  #define WTR(src,dst,K,N) k_wt<<<dim3((N)/64,(K)/64), dim3(256), 0, stream>>>((src),(dst),(K),(N))
  #define MM(Aptr,BTptr,biasptr,Cptr,M,N,K,act) \
    k_mm2<<<dim3((N)/128,(M)/128), dim3(256), 0, stream>>>((const ushort*)(Aptr),(const ushort*)(BTptr),(biasptr),(ushort*)(Cptr),(M),(N),(K),(act))
  #define MMH(Aptr,BTptr,biasptr,Cptr,M,N,K,act) \
    k_mm2h<<<dim3((N)/64,(M)/128), dim3(256), 0, stream>>>((const ushort*)(Aptr),(const ushort*)(BTptr),(biasptr),(ushort*)(Cptr),(M),(N),(K),(act))

  // ---- weight prep: fp32 [K][N] -> bf16 [N][K] ----
  WTR(wq,   wqT, 1024, 1024);
  WTR(wk,   wkT, 1024, 256);
  WTR(wv,   wvT, 1024, 256);
  WTR(wo,   woT, 1024, 1024);
  WTR(cwq,  cwqT,1024, 1024);
  WTR(cwk,  cwkT,2048, 1024);
  WTR(cwv,  cwvT,2048, 1024);
  WTR(cwo,  cwoT,1024, 1024);
  WTR(fc1_w,fc1T,1024, 4096);
  WTR(fc2_w,fc2T,4096, 1024);
  WTR(ct1_w,ct1T,2048, 512);
  WTR(ct2_w,ct2T,512,  3072);
  WTR(rf1_w,rf1T,1024, 2048);
  WTR(rf2_w,rf2T,2048, 1024);
  WTR(hg1_w,hg1T,1024, 256);

  // x -> X; mod = silu(c) @ ada_w + ada_b (K-split atomic GEMV)
  k_copy4<<<G1(NT/4), 0, stream>>>((const float4*)x_in, (float4*)X, NT/4);
  k_silu<<<G1(BB*DD), 0, stream>>>(c_in, SIL, BB*DD);
  k_adab<<<G1(BB*6144), 0, stream>>>(ada_b, MOD, BB*6144);
  k_ada2<<<dim3(6,32), dim3(256), 0, stream>>>(SIL, ada_w, MOD);

  // ---- self-attention ----
  k_rms<<<dim3(4096), dim3(256), 0, stream>>>(X, n1, MOD, DD, 0, Hh, 1);
  MM(Hh, wqT, nullptr, Qb, 4096, 1024, 1024, 0);
  MMH(Hh, wkT, nullptr, KP, 4096, 256, 1024, 0);
  MMH(Hh, wvT, nullptr, VP, 4096, 256, 1024, 0);
  k_rope<<<G1(BB*HH*NN*32), 0, stream>>>(Qb, cosw, sinw, QR, HH, BB*HH*NN*32);
  k_rope<<<G1(BB*KVH*NN*32), 0, stream>>>(KP, cosw, sinw, KR, KVH, BB*KVH*NN*32);
  k_trv<<<G1(BB*NN*KVH*64), 0, stream>>>(VP, VR, NN, KVH, BB*NN*KVH*64);
  k_fattn<<<dim3(BB*HH*(NN/64)), dim3(256), 0, stream>>>((const ushort*)QR, (const ushort*)KR,
      (const ushort*)VR, (ushort*)SAb, HH, KVH, NN, NN, scale);
  MM(SAb, woT, nullptr, Hh, 4096, 1024, 1024, 0);
  k_resid<<<G1(NT), 0, stream>>>(X, Hh, MOD, 2*DD, NT);

  // ---- cross-attention ----
  k_rms<<<dim3(4096), dim3(256), 0, stream>>>(X, n2, nullptr, 0, 0, Hh, 0);
  MM(Hh, cwqT, nullptr, Qb, 4096, 1024, 1024, 0);
  k_tr<<<G1(NT), 0, stream>>>(Qb, QR, NN, HH, NT);
  k_f2bfv<<<G1(BB*SS*CTXD), 0, stream>>>(ctx_in, CTXB, BB*SS*CTXD);
  MMH(CTXB, cwkT, nullptr, KP, 512, 1024, 2048, 0);
  MMH(CTXB, cwvT, nullptr, VP, 512, 1024, 2048, 0);
  k_tr<<<G1(BB*SS*HH*64), 0, stream>>>(KP, KR, SS, HH, BB*SS*HH*64);
  k_trv<<<G1(BB*SS*HH*64), 0, stream>>>(VP, VR, SS, HH, BB*SS*HH*64);
  k_fattn<<<dim3(BB*HH*(NN/64)), dim3(256), 0, stream>>>((const ushort*)QR, (const ushort*)KR,
      (const ushort*)VR, (ushort*)SAb, HH, HH, NN, SS, scale);
  MM(SAb, cwoT, nullptr, Hh, 4096, 1024, 1024, 0);
  k_resid<<<G1(NT), 0, stream>>>(X, Hh, nullptr, 0, NT);

  // ---- MLP ----
  k_rms<<<dim3(4096), dim3(256), 0, stream>>>(X, n3, MOD, 4*DD, 3*DD, Hh, 1);
  MM(Hh, fc1T, fc1_b, BIG, 4096, 4096, 1024, 1);
  MM(BIG, fc2T, fc2_b, Qb, 4096, 1024, 4096, 0);
  k_resid<<<G1(NT), 0, stream>>>(X, Qb, MOD, 5*DD, NT);

  // ---- integrator (NITER=2) ----
  k_zero16<<<G1(NT), 0, stream>>>((unsigned short*)VST, NT);
  for (int it = 0; it < 2; ++it){
    k_concat<<<G1(2*NT), 0, stream>>>(X, VST, BIG, 2*NT);
    MMH(BIG, ct1T, ct1_b, CT1, 4096, 512, 2048, 1);
    MM(CT1, ct2T, ct2_b, BIG, 4096, 3072, 512, 0);
    k_ctrl<<<G1(NT), 0, stream>>>(BIG, X, VST, XN, mu, NT);
    MMH(XN, hg1T, hg1_b, HG1, 4096, 256, 1024, 1);
    k_hg2<<<dim3(4096), dim3(64), 0, stream>>>(HG1, hg2_w, hg2_b, HP, out_hp, it);
    MM(XN, rf1T, rf1_b, BIG, 4096, 2048, 1024, 1);
    MM(BIG, rf2T, rf2_b, RFO, 4096, 1024, 2048, 0);
    k_integ<<<G1(NT), 0, stream>>>(X, HP, RFO, int_w, NT);
  }
  // ---- final output: FP32 ----
  k_copy4<<<G1(NT/4), 0, stream>>>((const float4*)X, (float4*)out_f, NT/4);
  #undef G1
  #undef WTR
  #undef MM
  #undef MMH
}

// Round 6
// 1086.218 us; speedup vs baseline: 2.3192x; 1.0355x over previous
//
#include <hip/hip_runtime.h>
#include <hip/hip_bf16.h>
#include <math.h>

typedef __hip_bfloat16 bf16;
typedef unsigned short ushort;
typedef __bf16 bf16x8 __attribute__((ext_vector_type(8)));
typedef unsigned short u16x8 __attribute__((ext_vector_type(8)));
typedef float f32x4 __attribute__((ext_vector_type(4)));

#define BB 4
#define NN 1024
#define DD 1024
#define HH 16
#define KVH 4
#define HDIM 64
#define SS 128
#define CTXD 2048
#define MLPDIM 4096

__device__ __forceinline__ float bf2f(bf16 v){ return __bfloat162float(v); }
__device__ __forceinline__ bf16 f2bf(float v){ return __float2bfloat16(v); }
__device__ __forceinline__ ushort fbits(float v){ bf16 h = __float2bfloat16(v); return *(ushort*)&h; }
__device__ __forceinline__ float ubf(ushort u){ unsigned int x = ((unsigned int)u) << 16; float f; *(unsigned int*)&f = x; return f; }
__device__ __forceinline__ float sigmf_(float x){ return 1.f/(1.f+expf(-x)); }
__device__ __forceinline__ float geluf_(float x){ return 0.5f*x*(1.f+erff(x*0.70710678118f)); }

// async global->LDS, 16B per lane; LDS dest = base + lane*16 (wave-uniform base)
typedef const __attribute__((address_space(1))) void* gas_t;
typedef __attribute__((address_space(3))) void* las_t;
__device__ __forceinline__ void gl2lds16(const void* g, void* l){
  __builtin_amdgcn_global_load_lds((gas_t)g, (las_t)l, 16, 0, 0);
}

// ---------- converts ----------
__global__ void k_copy4(const float4* __restrict__ in, float4* __restrict__ out, int n4){
  int i = blockIdx.x*256 + threadIdx.x;
  if (i < n4) out[i] = in[i];
}
__global__ void k_f2bfv(const float* __restrict__ in, bf16* __restrict__ out, int n){
  int i = blockIdx.x*256 + threadIdx.x;
  if (i < n) out[i] = f2bf(in[i]);
}
__global__ void k_silu(const float* __restrict__ c, float* __restrict__ out, int n){
  int i = blockIdx.x*256 + threadIdx.x;
  if (i < n){ float v = c[i]; out[i] = v*sigmf_(v); }
}
__global__ void k_zero16(unsigned short* __restrict__ p, int n){
  int i = blockIdx.x*256 + threadIdx.x;
  if (i < n) p[i] = 0;
}

// ---------- weight transpose+convert: in fp32 [K][N] -> out bf16 [N][K] ----------
__global__ __launch_bounds__(256) void k_wt(const float* __restrict__ in, bf16* __restrict__ out, int K, int N){
  __shared__ float t[64][65];
  int bn = blockIdx.x*64, bk = blockIdx.y*64;
  int tid = threadIdx.x;
  int c4 = (tid & 15)*4, r = tid >> 4;
  #pragma unroll
  for (int i = 0; i < 4; ++i){
    float4 v = *(const float4*)(in + (size_t)(bk + r + i*16)*N + bn + c4);
    t[c4+0][r+i*16] = v.x; t[c4+1][r+i*16] = v.y; t[c4+2][r+i*16] = v.z; t[c4+3][r+i*16] = v.w;
  }
  __syncthreads();
  int n = tid >> 2, k16 = (tid & 3)*16;
  bf16* orow = out + (size_t)(bn + n)*K + bk + k16;
  #pragma unroll
  for (int j = 0; j < 16; ++j) orow[j] = f2bf(t[n][k16 + j]);
}

// ---------- adaLN: mod = silu(c) @ ada_w + ada_b ----------
__global__ void k_adab(const float* __restrict__ b, float* __restrict__ mod, int n){
  int idx = blockIdx.x*256 + threadIdx.x;
  if (idx < n) mod[idx] = b[idx % 6144];
}
__global__ __launch_bounds__(256) void k_ada2(const float* __restrict__ sc, const float* __restrict__ w,
                       float* __restrict__ mod){
  __shared__ float sl[4][32];
  int tid = threadIdx.x;
  int col4 = blockIdx.x*1024 + tid*4;
  int k0 = blockIdx.y*32;
  if (tid < 128) sl[tid >> 5][tid & 31] = sc[(tid >> 5)*DD + k0 + (tid & 31)];
  __syncthreads();
  f32x4 acc[4] = {};
  for (int kk = 0; kk < 32; ++kk){
    const float4 wv4 = *(const float4*)(w + (size_t)(k0 + kk)*6144 + col4);
    #pragma unroll
    for (int b = 0; b < 4; ++b){
      float s = sl[b][kk];
      acc[b][0] += s*wv4.x; acc[b][1] += s*wv4.y; acc[b][2] += s*wv4.z; acc[b][3] += s*wv4.w;
    }
  }
  #pragma unroll
  for (int b = 0; b < 4; ++b)
    #pragma unroll
    for (int j = 0; j < 4; ++j)
      atomicAdd(&mod[(size_t)b*6144 + col4 + j], acc[b][j]);
}

// ---------- RMSNorm (+optional adaLN scale/shift) ----------
__global__ __launch_bounds__(256) void k_rms(const float* __restrict__ X, const float* __restrict__ w,
                      const float* __restrict__ mod, int sc_off, int sh_off,
                      bf16* __restrict__ out, int use_mod){
  __shared__ float red[256];
  int row = blockIdx.x;
  int b = row >> 10;
  int tid = threadIdx.x;
  const float* xr = X + (size_t)row*DD;
  float s = 0.f;
  #pragma unroll
  for (int i = 0; i < 4; ++i){ float v = xr[tid + i*256]; s += v*v; }
  red[tid] = s; __syncthreads();
  for (int st = 128; st > 0; st >>= 1){ if (tid < st) red[tid] += red[tid+st]; __syncthreads(); }
  float rstd = rsqrtf(red[0]*(1.f/DD) + 1e-6f);
  bf16* orow = out + (size_t)row*DD;
  const float* mrow = use_mod ? (mod + (size_t)b*6*DD) : nullptr;
  #pragma unroll
  for (int i = 0; i < 4; ++i){
    int d = tid + i*256;
    float v = xr[d]*rstd*w[d];
    if (use_mod) v = v*(1.f + mrow[sc_off + d]) + mrow[sh_off + d];
    orow[d] = f2bf(v);
  }
}

// ---------- MFMA GEMM v2: C(MxN,bf16) = A(MxK,bf16) @ BT(NxK,bf16)^T [+bias][gelu] ----------
// 128x128 tile, BK=64, gl2lds staging, XOR-swizzled LDS (T2 + rule 21).
__global__ __launch_bounds__(256,2) void k_mm2(const ushort* __restrict__ A, const ushort* __restrict__ BT,
                      const float* __restrict__ bias, ushort* __restrict__ C,
                      int M, int N, int K, int act){
  __shared__ ushort As[128*64];   // phys [row][kphys]; logical k-slot t at phys slot t^(row&7)
  __shared__ ushort Bs[128*64];
  int tid = threadIdx.x, lane = tid & 63, wv = tid >> 6;
  int l15 = lane & 15, quad = lane >> 4;
  int bm = blockIdx.y*128, bn = blockIdx.x*128;
  int wm = (wv & 1)*64, wn = (wv >> 1)*64;
  int lr = lane >> 3, lc = lane & 7;
  int ksw = (lc ^ lr) << 3;
  f32x4 acc[4][4] = {};
  const ushort* Abase = A  + (size_t)(bm + wv*32 + lr)*K + ksw;
  const ushort* Bbase = BT + (size_t)(bn + wv*32 + lr)*K + ksw;
  ushort* AsW = As + wv*2048;
  ushort* BsW = Bs + wv*2048;
  int swr = (l15 & 7) << 3;
  for (int k0 = 0; k0 < K; k0 += 64){
    #pragma unroll
    for (int i = 0; i < 4; ++i){
      gl2lds16(Abase + k0 + (size_t)(i*8)*K, AsW + i*512);
      gl2lds16(Bbase + k0 + (size_t)(i*8)*K, BsW + i*512);
    }
    __syncthreads();
    #pragma unroll
    for (int ks = 0; ks < 2; ++ks){
      bf16x8 af[4], bfr[4];
      #pragma unroll
      for (int mi = 0; mi < 4; ++mi){
        int r = wm + mi*16 + l15;
        af[mi] = __builtin_bit_cast(bf16x8, *(const uint4*)(As + r*64 + ((ks*32 + quad*8) ^ swr)));
      }
      #pragma unroll
      for (int nj = 0; nj < 4; ++nj){
        int r = wn + nj*16 + l15;
        bfr[nj] = __builtin_bit_cast(bf16x8, *(const uint4*)(Bs + r*64 + ((ks*32 + quad*8) ^ swr)));
      }
      #pragma unroll
      for (int mi = 0; mi < 4; ++mi)
        #pragma unroll
        for (int nj = 0; nj < 4; ++nj)
          acc[mi][nj] = __builtin_amdgcn_mfma_f32_16x16x32_bf16(af[mi], bfr[nj], acc[mi][nj], 0, 0, 0);
    }
    __syncthreads();
  }
  #pragma unroll
  for (int nj = 0; nj < 4; ++nj){
    int col = bn + wn + nj*16 + l15;
    float bv = bias ? bias[col] : 0.f;
    #pragma unroll
    for (int mi = 0; mi < 4; ++mi){
      #pragma unroll
      for (int r = 0; r < 4; ++r){
        int row = bm + wm + mi*16 + quad*4 + r;
        float v = acc[mi][nj][r] + bv;
        if (act) v = geluf_(v);
        C[(size_t)row*N + col] = fbits(v);
      }
    }
  }
}

// ---------- MFMA GEMM half-width: BM=128, BN=64 — for grid-starved (skinny) GEMMs ----------
__global__ __launch_bounds__(256,2) void k_mm2h(const ushort* __restrict__ A, const ushort* __restrict__ BT,
                      const float* __restrict__ bias, ushort* __restrict__ C,
                      int M, int N, int K, int act){
  __shared__ ushort As[128*64];
  __shared__ ushort Bs[64*64];
  int tid = threadIdx.x, lane = tid & 63, wv = tid >> 6;
  int l15 = lane & 15, quad = lane >> 4;
  int bm = blockIdx.y*128, bn = blockIdx.x*64;
  int wm = wv*32;
  int lr = lane >> 3, lc = lane & 7;
  int ksw = (lc ^ lr) << 3;
  f32x4 acc[2][4] = {};
  const ushort* Abase = A  + (size_t)(bm + wv*32 + lr)*K + ksw;
  const ushort* Bbase = BT + (size_t)(bn + wv*16 + lr)*K + ksw;
  ushort* AsW = As + wv*2048;
  ushort* BsW = Bs + wv*1024;
  int swr = (l15 & 7) << 3;
  for (int k0 = 0; k0 < K; k0 += 64){
    #pragma unroll
    for (int i = 0; i < 4; ++i)
      gl2lds16(Abase + k0 + (size_t)(i*8)*K, AsW + i*512);
    #pragma unroll
    for (int i = 0; i < 2; ++i)
      gl2lds16(Bbase + k0 + (size_t)(i*8)*K, BsW + i*512);
    __syncthreads();
    #pragma unroll
    for (int ks = 0; ks < 2; ++ks){
      bf16x8 af[2], bfr[4];
      #pragma unroll
      for (int mi = 0; mi < 2; ++mi){
        int r = wm + mi*16 + l15;
        af[mi] = __builtin_bit_cast(bf16x8, *(const uint4*)(As + r*64 + ((ks*32 + quad*8) ^ swr)));
      }
      #pragma unroll
      for (int nj = 0; nj < 4; ++nj){
        int r = nj*16 + l15;
        bfr[nj] = __builtin_bit_cast(bf16x8, *(const uint4*)(Bs + r*64 + ((ks*32 + quad*8) ^ swr)));
      }
      #pragma unroll
      for (int mi = 0; mi < 2; ++mi)
        #pragma unroll
        for (int nj = 0; nj < 4; ++nj)
          acc[mi][nj] = __builtin_amdgcn_mfma_f32_16x16x32_bf16(af[mi], bfr[nj], acc[mi][nj], 0, 0, 0);
    }
    __syncthreads();
  }
  #pragma unroll
  for (int nj = 0; nj < 4; ++nj){
    int col = bn + nj*16 + l15;
    float bv = bias ? bias[col] : 0.f;
    #pragma unroll
    for (int mi = 0; mi < 2; ++mi){
      #pragma unroll
      for (int r = 0; r < 4; ++r){
        int row = bm + wm + mi*16 + quad*4 + r;
        float v = acc[mi][nj][r] + bv;
        if (act) v = geluf_(v);
        C[(size_t)row*N + col] = fbits(v);
      }
    }
  }
}

// ---------- RoPE: in (B,NN,NHp,64) -> out (B,NHp,NN,64), rotated ----------
__global__ void k_rope(const bf16* __restrict__ in, const float* __restrict__ cw,
                       const float* __restrict__ sw, bf16* __restrict__ out, int NHp, int n){
  int idx = blockIdx.x*256 + threadIdx.x;
  if (idx >= n) return;
  int d2 = idx & 31; int t = idx >> 5;
  int nn = t % NN; t /= NN; int h = t % NHp; int b = t / NHp;
  const bf16* base = in + ((size_t)((b*NN+nn)*NHp + h))*HDIM;
  float e = bf2f(base[2*d2]), o = bf2f(base[2*d2+1]);
  float c = cw[nn*32 + d2], s = sw[nn*32 + d2];
  bf16* ob = out + ((size_t)((b*NHp+h)*NN + nn))*HDIM;
  ob[d2]      = f2bf(e*c - o*s);
  ob[32 + d2] = f2bf(e*s + o*c);
}

// ---------- transpose (B,T,NHp,64) -> (B,NHp,T,64) ----------
__global__ void k_tr(const bf16* __restrict__ in, bf16* __restrict__ out, int T, int NHp, int n){
  int idx = blockIdx.x*256 + threadIdx.x;
  if (idx >= n) return;
  int d = idx & 63; int t = idx >> 6;
  int h = t % NHp; t /= NHp; int tok = t % T; int b = t / T;
  out[((size_t)((b*NHp+h)*T + tok))*64 + d] = in[idx];
}

// ---------- V transpose (B,T,NHp,64) -> (B,NHp,64,T) ----------
__global__ void k_trv(const bf16* __restrict__ in, bf16* __restrict__ out, int T, int NHp, int n){
  int idx = blockIdx.x*256 + threadIdx.x;
  if (idx >= n) return;
  int d = idx & 63; int t = idx >> 6;
  int h = t % NHp; t /= NHp; int tok = t % T; int b = t / T;
  out[((size_t)(b*NHp+h)*64 + d)*T + tok] = in[idx];
}

// ---------- MFMA flash attention ----------
// T13 defer-max softmax in base-2: m starts at 0, cross-lane reduces + rescales only when
// __any(local_max - m > 8) (softmax is shift-invariant; fallback bounds P <= 2^8).
// Row-sum kept as per-thread partial, reduced once at the end. log2(e) folded into Q scale.
__global__ __launch_bounds__(256) void k_fattn(const ushort* __restrict__ Q, const ushort* __restrict__ K,
                      const ushort* __restrict__ V, ushort* __restrict__ O,
                      int NH, int NKV, int Nq, int Nk, float scale){
  __shared__ ushort Kt[64*64];
  __shared__ ushort Vt[64*64];
  __shared__ ushort Ps[4][16*72];  // per-wave [q][key], stride 72
  int tid = threadIdx.x, lane = tid & 63, wv = tid >> 6;
  int l15 = lane & 15, quad = lane >> 4;
  int lr = lane >> 3, lc = lane & 7;
  int ksw = (lc ^ lr) << 3;
  int swr = (l15 & 7) << 3;
  int nqt = Nq >> 6;
  int qt = blockIdx.x % nqt; int t = blockIdx.x / nqt; int h = t % NH; int b = t / NH;
  int kvh = h / (NH / NKV);
  const ushort* Kb = K + (size_t)(b*NKV+kvh)*Nk*64 + ksw;
  const ushort* Vb = V + (size_t)(b*NKV+kvh)*64*Nk + ksw;
  const ushort* Qp = Q + ((size_t)((b*NH+h)*Nq + qt*64 + wv*16 + l15))*64;
  // fold softmax scale AND log2(e) into Q (scores land in log2 domain)
  float qscale = scale * 1.44269504f;
  uint4 qraw0 = *(const uint4*)(Qp + quad*8);
  uint4 qraw1 = *(const uint4*)(Qp + 32 + quad*8);
  u16x8 q0 = __builtin_bit_cast(u16x8, qraw0), q1 = __builtin_bit_cast(u16x8, qraw1);
  #pragma unroll
  for (int j = 0; j < 8; ++j){ q0[j] = fbits(ubf(q0[j])*qscale); q1[j] = fbits(ubf(q1[j])*qscale); }
  bf16x8 qf0 = __builtin_bit_cast(bf16x8, q0);
  bf16x8 qf1 = __builtin_bit_cast(bf16x8, q1);
  f32x4 acc[4] = {};
  float m_run[4]  = {0.f,0.f,0.f,0.f};
  float l_part[4] = {0.f,0.f,0.f,0.f};
  ushort* Pw = Ps[wv];
  int wrow = wv*16;   // this wave stages rows wrow..wrow+15 (two 8-row chunks)
  for (int t0 = 0; t0 < Nk; t0 += 64){
    #pragma unroll
    for (int i = 0; i < 2; ++i){
      int row = wrow + i*8 + lr;
      gl2lds16(Kb + (size_t)(t0+row)*64, Kt + (wrow + i*8)*64);
      gl2lds16(Vb + (size_t)row*Nk + t0, Vt + (wrow + i*8)*64);
    }
    __syncthreads();
    // S = Q @ K^T (log2-domain)
    f32x4 s[4] = {};
    __builtin_amdgcn_s_setprio(1);
    #pragma unroll
    for (int nj = 0; nj < 4; ++nj){
      const ushort* kr = Kt + (nj*16+l15)*64;
      bf16x8 kf0 = __builtin_bit_cast(bf16x8, *(const uint4*)(kr + ((quad*8) ^ swr)));
      s[nj] = __builtin_amdgcn_mfma_f32_16x16x32_bf16(qf0, kf0, s[nj], 0, 0, 0);
      bf16x8 kf1 = __builtin_bit_cast(bf16x8, *(const uint4*)(kr + ((32 + quad*8) ^ swr)));
      s[nj] = __builtin_amdgcn_mfma_f32_16x16x32_bf16(qf1, kf1, s[nj], 0, 0, 0);
    }
    __builtin_amdgcn_s_setprio(0);
    // defer-max online softmax; row = quad*4+r
    float tl[4];
    #pragma unroll
    for (int r = 0; r < 4; ++r)
      tl[r] = fmaxf(fmaxf(s[0][r], s[1][r]), fmaxf(s[2][r], s[3][r]));
    float dmax = fmaxf(fmaxf(tl[0]-m_run[0], tl[1]-m_run[1]),
                       fmaxf(tl[2]-m_run[2], tl[3]-m_run[3]));
    if (__any(dmax > 8.f)){
      #pragma unroll
      for (int r = 0; r < 4; ++r){
        float tm = tl[r];
        #pragma unroll
        for (int off = 8; off; off >>= 1) tm = fmaxf(tm, __shfl_xor(tm, off, 64));
        float mn = fmaxf(m_run[r], tm);
        float al = exp2f(m_run[r] - mn);
        m_run[r] = mn;
        l_part[r] *= al;
        #pragma unroll
        for (int nj = 0; nj < 4; ++nj) acc[nj][r] *= al;
      }
    }
    #pragma unroll
    for (int nj = 0; nj < 4; ++nj)
      #pragma unroll
      for (int r = 0; r < 4; ++r){
        float p = exp2f(s[nj][r] - m_run[r]);
        s[nj][r] = p;
        Pw[(quad*4+r)*72 + nj*16 + l15] = fbits(p);
      }
    #pragma unroll
    for (int r = 0; r < 4; ++r)
      l_part[r] += (s[0][r]+s[1][r]) + (s[2][r]+s[3][r]);
    // O += P @ V  (P in wave-private LDS; same-wave ordering, no barrier)
    bf16x8 pf0 = __builtin_bit_cast(bf16x8, *(const uint4*)(Pw + l15*72 + quad*8));
    bf16x8 pf1 = __builtin_bit_cast(bf16x8, *(const uint4*)(Pw + l15*72 + 32 + quad*8));
    __builtin_amdgcn_s_setprio(1);
    #pragma unroll
    for (int nj = 0; nj < 4; ++nj){
      const ushort* vr = Vt + (nj*16+l15)*64;
      bf16x8 vf0 = __builtin_bit_cast(bf16x8, *(const uint4*)(vr + ((quad*8) ^ swr)));
      acc[nj] = __builtin_amdgcn_mfma_f32_16x16x32_bf16(pf0, vf0, acc[nj], 0, 0, 0);
      bf16x8 vf1 = __builtin_bit_cast(bf16x8, *(const uint4*)(vr + ((32 + quad*8) ^ swr)));
      acc[nj] = __builtin_amdgcn_mfma_f32_16x16x32_bf16(pf1, vf1, acc[nj], 0, 0, 0);
    }
    __builtin_amdgcn_s_setprio(0);
    __syncthreads();
  }
  // final row-sum reduce (once, not per tile)
  float inv[4];
  #pragma unroll
  for (int r = 0; r < 4; ++r){
    float ls = l_part[r];
    #pragma unroll
    for (int off = 8; off; off >>= 1) ls += __shfl_xor(ls, off, 64);
    inv[r] = 1.f / ls;
  }
  int nbase = qt*64 + wv*16 + quad*4;
  #pragma unroll
  for (int r = 0; r < 4; ++r){
    size_t ob = ((size_t)((b*Nq + nbase + r)*NH + h))*64;
    #pragma unroll
    for (int nj = 0; nj < 4; ++nj)
      O[ob + nj*16 + l15] = fbits(acc[nj][r]*inv[r]);
  }
}

// ---------- residual: X = (base? base : X) + (mod? g : 1) * val ----------
__global__ void k_resid(float* __restrict__ X, const float* __restrict__ base,
                        const bf16* __restrict__ val,
                        const float* __restrict__ mod, int goff, int n){
  int i = blockIdx.x*256 + threadIdx.x;
  if (i >= n) return;
  float g = 1.f;
  if (mod){ int b = i >> 20; int d = i & 1023; g = mod[b*6144 + goff + d]; }
  float x0 = base ? base[i] : X[i];
  X[i] = x0 + g*bf2f(val[i]);
}

// ---------- concat [X(fp32), VST(bf16)] -> CAT bf16 ----------
__global__ void k_concat(const float* __restrict__ X, const bf16* __restrict__ V,
                         bf16* __restrict__ C, int n){
  int i = blockIdx.x*256 + threadIdx.x;
  if (i >= n) return;
  int row = i >> 11, col = i & 2047;
  C[i] = (col < 1024) ? f2bf(X[(size_t)row*1024 + col]) : V[(size_t)row*1024 + col - 1024];
}

// ---------- integrator control update ----------
__global__ void k_ctrl(const bf16* __restrict__ ctrl, const float* __restrict__ X,
                       bf16* __restrict__ VST, bf16* __restrict__ XN,
                       const float* __restrict__ mu, int n){
  int i = blockIdx.x*256 + threadIdx.x;
  if (i >= n) return;
  int row = i >> 10, d = i & 1023;
  const bf16* cr = ctrl + (size_t)row*3072;
  float alpha = sigmf_(bf2f(cr[d]));
  float braw  = bf2f(cr[1024 + d]);
  float beta  = fmaxf(braw, 0.f) + log1pf(expf(-fabsf(braw)));
  float gate  = sigmf_(bf2f(cr[2048 + d]));
  float vn = alpha*bf2f(VST[i]) - beta*(X[i] - mu[d]);
  VST[i] = f2bf(vn);
  XN[i]  = f2bf(X[i] + 0.1f*gate*vn);
}

// ---------- hg2: hp = sigmoid(hg1out @ w + b) ; fp32 halt tail ----------
__global__ __launch_bounds__(64) void k_hg2(const bf16* __restrict__ hin, const float* __restrict__ w,
                     const float* __restrict__ bb, float* __restrict__ hp,
                     float* __restrict__ oout, int it){
  int r = blockIdx.x; int lane = threadIdx.x;
  const bf16* hr = hin + (size_t)r*256;
  float s = 0.f;
  #pragma unroll
  for (int i = 0; i < 4; ++i) s += bf2f(hr[lane + i*64])*w[lane + i*64];
  for (int off = 32; off; off >>= 1) s += __shfl_xor(s, off, 64);
  if (lane == 0){
    float v = sigmf_(s + bb[0]);
    hp[r] = v;
    int b = r >> 10, nn = r & 1023;
    oout[((size_t)(b*2 + it) << 10) + nn] = v;
  }
}

// ---------- integ += hp * refined * int_w ----------
__global__ void k_integ(float* __restrict__ X, const float* __restrict__ hp,
                        const bf16* __restrict__ rf, const float* __restrict__ iw, int n){
  int i = blockIdx.x*256 + threadIdx.x;
  if (i >= n) return;
  int row = i >> 10, d = i & 1023;
  X[i] += hp[row]*bf2f(rf[i])*iw[d];
}

extern "C" void kernel_launch(void* const* d_in, const int* in_sizes, int n_in,
                              void* d_out, int out_size, void* d_ws, size_t ws_size,
                              hipStream_t stream) {
  const float* x_in  = (const float*)d_in[0];
  const float* c_in  = (const float*)d_in[1];
  const float* ctx_in= (const float*)d_in[2];
  const float* cosw  = (const float*)d_in[3];
  const float* sinw  = (const float*)d_in[4];
  const float* wq    = (const float*)d_in[5];
  const float* wk    = (const float*)d_in[6];
  const float* wv    = (const float*)d_in[7];
  const float* wo    = (const float*)d_in[8];
  const float* cwq   = (const float*)d_in[9];
  const float* cwk   = (const float*)d_in[10];
  const float* cwv   = (const float*)d_in[11];
  const float* cwo   = (const float*)d_in[12];
  const float* fc1_w = (const float*)d_in[13];
  const float* fc1_b = (const float*)d_in[14];
  const float* fc2_w = (const float*)d_in[15];
  const float* fc2_b = (const float*)d_in[16];
  const float* ada_w = (const float*)d_in[17];
  const float* ada_b = (const float*)d_in[18];
  const float* n1    = (const float*)d_in[19];
  const float* n2    = (const float*)d_in[20];
  const float* n3    = (const float*)d_in[21];
  const float* int_w = (const float*)d_in[22];
  const float* mu    = (const float*)d_in[23];
  const float* hg1_w = (const float*)d_in[24];
  const float* hg1_b = (const float*)d_in[25];
  const float* hg2_w = (const float*)d_in[26];
  const float* hg2_b = (const float*)d_in[27];
  const float* ct1_w = (const float*)d_in[28];
  const float* ct1_b = (const float*)d_in[29];
  const float* ct2_w = (const float*)d_in[30];
  const float* ct2_b = (const float*)d_in[31];
  const float* rf1_w = (const float*)d_in[32];
  const float* rf1_b = (const float*)d_in[33];
  const float* rf2_w = (const float*)d_in[34];
  const float* rf2_b = (const float*)d_in[35];

  float* out_f  = (float*)d_out;
  float* out_hp = out_f + (size_t)BB*NN*DD;

  // ---- workspace map (~112 MB) ----
  char* wsb = (char*)d_ws;
  const size_t Mi = 1u << 20;
  float* X  = (float*)wsb;                    // [0,16MB)
  bf16*  Hh = (bf16*)(wsb + 16*Mi);           // [16,24MB)
  bf16*  Qb = (bf16*)(wsb + 24*Mi);           // [24,32MB)
  bf16*  R  = (bf16*)(wsb + 32*Mi);           // [32,64MB)
  bf16*  QR  = R;
  bf16*  SAb = R + 4*Mi;
  bf16*  KP  = R + 8*Mi;
  bf16*  VP  = R + 9*Mi;
  bf16*  KR  = R + 10*Mi;
  bf16*  VR  = R + 11*Mi;
  bf16*  CTXB= R + 12*Mi;
  bf16*  BIG = R;
  bf16*  CT1 = R + 12*Mi;
  bf16*  HG1 = R + 12*Mi;
  bf16*  RFO = R + 8*Mi;
  float* SIL = (float*)(wsb + 64*Mi);
  float* MOD = SIL + 4096;
  float* HP  = MOD + 24576;
  bf16*  VST = Qb;
  bf16*  XN  = Hh;
  // transposed bf16 weights [N][K] at +65MB (46.5MB)
  bf16* WT   = (bf16*)(wsb + 65*Mi);
  bf16* wqT  = WT;                 // 1024x1024
  bf16* wkT  = wqT  + 1048576;     // 256x1024
  bf16* wvT  = wkT  + 262144;      // 256x1024
  bf16* woT  = wvT  + 262144;      // 1024x1024
  bf16* cwqT = woT  + 1048576;     // 1024x1024
  bf16* cwkT = cwqT + 1048576;     // 1024x2048
  bf16* cwvT = cwkT + 2097152;     // 1024x2048
  bf16* cwoT = cwvT + 2097152;     // 1024x1024
  bf16* fc1T = cwoT + 1048576;     // 4096x1024
  bf16* fc2T = fc1T + 4194304;     // 1024x4096
  bf16* ct1T = fc2T + 4194304;     // 512x2048
  bf16* ct2T = ct1T + 1048576;     // 3072x512
  bf16* rf1T = ct2T + 1572864;     // 2048x1024
  bf16* rf2T = rf1T + 2097152;     // 1024x2048
  bf16* hg1T = rf2T + 2097152;     // 256x1024

  const int NT = BB*NN*DD;
  const float scale = 0.125f;
  #define G1(n) dim3(((n)+255)/256), dim3(256)
  #define WTR(src,dst,K,N) k_wt<<<dim3((N)/64,(K)/64), dim3(256), 0, stream>>>((src),(dst),(K),(N))
  #define MM(Aptr,BTptr,biasptr,Cptr,M,N,K,act) \
    k_mm2<<<dim3((N)/128,(M)/128), dim3(256), 0, stream>>>((const ushort*)(Aptr),(const ushort*)(BTptr),(biasptr),(ushort*)(Cptr),(M),(N),(K),(act))
  #define MMH(Aptr,BTptr,biasptr,Cptr,M,N,K,act) \
    k_mm2h<<<dim3((N)/64,(M)/128), dim3(256), 0, stream>>>((const ushort*)(Aptr),(const ushort*)(BTptr),(biasptr),(ushort*)(Cptr),(M),(N),(K),(act))

  // ---- weight prep: fp32 [K][N] -> bf16 [N][K] ----
  WTR(wq,   wqT, 1024, 1024);
  WTR(wk,   wkT, 1024, 256);
  WTR(wv,   wvT, 1024, 256);
  WTR(wo,   woT, 1024, 1024);
  WTR(cwq,  cwqT,1024, 1024);
  WTR(cwk,  cwkT,2048, 1024);
  WTR(cwv,  cwvT,2048, 1024);
  WTR(cwo,  cwoT,1024, 1024);
  WTR(fc1_w,fc1T,1024, 4096);
  WTR(fc2_w,fc2T,4096, 1024);
  WTR(ct1_w,ct1T,2048, 512);
  WTR(ct2_w,ct2T,512,  3072);
  WTR(rf1_w,rf1T,1024, 2048);
  WTR(rf2_w,rf2T,2048, 1024);
  WTR(hg1_w,hg1T,1024, 256);

  // mod = silu(c) @ ada_w + ada_b (K-split atomic GEMV). No x copy: first RMS reads x_in.
  k_silu<<<G1(BB*DD), 0, stream>>>(c_in, SIL, BB*DD);
  k_adab<<<G1(BB*6144), 0, stream>>>(ada_b, MOD, BB*6144);
  k_ada2<<<dim3(6,32), dim3(256), 0, stream>>>(SIL, ada_w, MOD);

  // ---- self-attention ----
  k_rms<<<dim3(4096), dim3(256), 0, stream>>>(x_in, n1, MOD, DD, 0, Hh, 1);
  MM(Hh, wqT, nullptr, Qb, 4096, 1024, 1024, 0);
  MMH(Hh, wkT, nullptr, KP, 4096, 256, 1024, 0);
  MMH(Hh, wvT, nullptr, VP, 4096, 256, 1024, 0);
  k_rope<<<G1(BB*HH*NN*32), 0, stream>>>(Qb, cosw, sinw, QR, HH, BB*HH*NN*32);
  k_rope<<<G1(BB*KVH*NN*32), 0, stream>>>(KP, cosw, sinw, KR, KVH, BB*KVH*NN*32);
  k_trv<<<G1(BB*NN*KVH*64), 0, stream>>>(VP, VR, NN, KVH, BB*NN*KVH*64);
  k_fattn<<<dim3(BB*HH*(NN/64)), dim3(256), 0, stream>>>((const ushort*)QR, (const ushort*)KR,
      (const ushort*)VR, (ushort*)SAb, HH, KVH, NN, NN, scale);
  MM(SAb, woT, nullptr, Hh, 4096, 1024, 1024, 0);
  k_resid<<<G1(NT), 0, stream>>>(X, x_in, Hh, MOD, 2*DD, NT);

  // ---- cross-attention ----
  k_rms<<<dim3(4096), dim3(256), 0, stream>>>(X, n2, nullptr, 0, 0, Hh, 0);
  MM(Hh, cwqT, nullptr, Qb, 4096, 1024, 1024, 0);
  k_tr<<<G1(NT), 0, stream>>>(Qb, QR, NN, HH, NT);
  k_f2bfv<<<G1(BB*SS*CTXD), 0, stream>>>(ctx_in, CTXB, BB*SS*CTXD);
  MMH(CTXB, cwkT, nullptr, KP, 512, 1024, 2048, 0);
  MMH(CTXB, cwvT, nullptr, VP, 512, 1024, 2048, 0);
  k_tr<<<G1(BB*SS*HH*64), 0, stream>>>(KP, KR, SS, HH, BB*SS*HH*64);
  k_trv<<<G1(BB*SS*HH*64), 0, stream>>>(VP, VR, SS, HH, BB*SS*HH*64);
  k_fattn<<<dim3(BB*HH*(NN/64)), dim3(256), 0, stream>>>((const ushort*)QR, (const ushort*)KR,
      (const ushort*)VR, (ushort*)SAb, HH, HH, NN, SS, scale);
  MM(SAb, cwoT, nullptr, Hh, 4096, 1024, 1024, 0);
  k_resid<<<G1(NT), 0, stream>>>(X, nullptr, Hh, nullptr, 0, NT);

  // ---- MLP ----
  k_rms<<<dim3(4096), dim3(256), 0, stream>>>(X, n3, MOD, 4*DD, 3*DD, Hh, 1);
  MM(Hh, fc1T, fc1_b, BIG, 4096, 4096, 1024, 1);
  MM(BIG, fc2T, fc2_b, Qb, 4096, 1024, 4096, 0);
  k_resid<<<G1(NT), 0, stream>>>(X, nullptr, Qb, MOD, 5*DD, NT);

  // ---- integrator (NITER=2) ----
  k_zero16<<<G1(NT), 0, stream>>>((unsigned short*)VST, NT);
  for (int it = 0; it < 2; ++it){
    k_concat<<<G1(2*NT), 0, stream>>>(X, VST, BIG, 2*NT);
    MMH(BIG, ct1T, ct1_b, CT1, 4096, 512, 2048, 1);
    MM(CT1, ct2T, ct2_b, BIG, 4096, 3072, 512, 0);
    k_ctrl<<<G1(NT), 0, stream>>>(BIG, X, VST, XN, mu, NT);
    MMH(XN, hg1T, hg1_b, HG1, 4096, 256, 1024, 1);
    k_hg2<<<dim3(4096), dim3(64), 0, stream>>>(HG1, hg2_w, hg2_b, HP, out_hp, it);
    MM(XN, rf1T, rf1_b, BIG, 4096, 2048, 1024, 1);
    MM(BIG, rf2T, rf2_b, RFO, 4096, 1024, 2048, 0);
    k_integ<<<G1(NT), 0, stream>>>(X, HP, RFO, int_w, NT);
  }
  // ---- final output: FP32 ----
  k_copy4<<<G1(NT/4), 0, stream>>>((const float4*)X, (float4*)out_f, NT/4);
  #undef G1
  #undef WTR
  #undef MM
  #undef MMH
}

// Round 7
// 1043.961 us; speedup vs baseline: 2.4131x; 1.0405x over previous
//
#include <hip/hip_runtime.h>
#include <hip/hip_bf16.h>
#include <math.h>

typedef __hip_bfloat16 bf16;
typedef unsigned short ushort;
typedef __bf16 bf16x8 __attribute__((ext_vector_type(8)));
typedef unsigned short u16x8 __attribute__((ext_vector_type(8)));
typedef float f32x4 __attribute__((ext_vector_type(4)));

#define BB 4
#define NN 1024
#define DD 1024
#define HH 16
#define KVH 4
#define HDIM 64
#define SS 128
#define CTXD 2048
#define MLPDIM 4096

__device__ __forceinline__ float bf2f(bf16 v){ return __bfloat162float(v); }
__device__ __forceinline__ bf16 f2bf(float v){ return __float2bfloat16(v); }
__device__ __forceinline__ ushort fbits(float v){ bf16 h = __float2bfloat16(v); return *(ushort*)&h; }
__device__ __forceinline__ float ubf(ushort u){ unsigned int x = ((unsigned int)u) << 16; float f; *(unsigned int*)&f = x; return f; }
__device__ __forceinline__ float sigmf_(float x){ return 1.f/(1.f+expf(-x)); }
__device__ __forceinline__ float geluf_(float x){ return 0.5f*x*(1.f+erff(x*0.70710678118f)); }

// async global->LDS, 16B per lane; LDS dest = base + lane*16 (wave-uniform base)
typedef const __attribute__((address_space(1))) void* gas_t;
typedef __attribute__((address_space(3))) void* las_t;
__device__ __forceinline__ void gl2lds16(const void* g, void* l){
  __builtin_amdgcn_global_load_lds((gas_t)g, (las_t)l, 16, 0, 0);
}

// T1: bijective XCD swizzle (requires total%8==0 — all our grids satisfy this).
// Consecutive-orig blocks land on the same XCD and get consecutive tiles -> L2 panel reuse.
__device__ __forceinline__ int xcd_swz_flat(int flat, int total){
  return (flat & 7)*(total >> 3) + (flat >> 3);
}

// ---------- converts ----------
__global__ void k_copy4(const float4* __restrict__ in, float4* __restrict__ out, int n4){
  int i = blockIdx.x*256 + threadIdx.x;
  if (i < n4) out[i] = in[i];
}
__global__ void k_f2bfv(const float* __restrict__ in, bf16* __restrict__ out, int n){
  int i = blockIdx.x*256 + threadIdx.x;
  if (i < n) out[i] = f2bf(in[i]);
}
__global__ void k_silu(const float* __restrict__ c, float* __restrict__ out, int n){
  int i = blockIdx.x*256 + threadIdx.x;
  if (i < n){ float v = c[i]; out[i] = v*sigmf_(v); }
}
__global__ void k_zero16(unsigned short* __restrict__ p, int n){
  int i = blockIdx.x*256 + threadIdx.x;
  if (i < n) p[i] = 0;
}

// ---------- weight transpose+convert: in fp32 [K][N] -> out bf16 [N][K] ----------
__global__ __launch_bounds__(256) void k_wt(const float* __restrict__ in, bf16* __restrict__ out, int K, int N){
  __shared__ float t[64][65];
  int bn = blockIdx.x*64, bk = blockIdx.y*64;
  int tid = threadIdx.x;
  int c4 = (tid & 15)*4, r = tid >> 4;
  #pragma unroll
  for (int i = 0; i < 4; ++i){
    float4 v = *(const float4*)(in + (size_t)(bk + r + i*16)*N + bn + c4);
    t[c4+0][r+i*16] = v.x; t[c4+1][r+i*16] = v.y; t[c4+2][r+i*16] = v.z; t[c4+3][r+i*16] = v.w;
  }
  __syncthreads();
  int n = tid >> 2, k16 = (tid & 3)*16;
  bf16* orow = out + (size_t)(bn + n)*K + bk + k16;
  #pragma unroll
  for (int j = 0; j < 16; ++j) orow[j] = f2bf(t[n][k16 + j]);
}

// ---------- adaLN: mod = silu(c) @ ada_w + ada_b ----------
__global__ void k_adab(const float* __restrict__ b, float* __restrict__ mod, int n){
  int idx = blockIdx.x*256 + threadIdx.x;
  if (idx < n) mod[idx] = b[idx % 6144];
}
__global__ __launch_bounds__(256) void k_ada2(const float* __restrict__ sc, const float* __restrict__ w,
                       float* __restrict__ mod){
  __shared__ float sl[4][32];
  int tid = threadIdx.x;
  int col4 = blockIdx.x*1024 + tid*4;
  int k0 = blockIdx.y*32;
  if (tid < 128) sl[tid >> 5][tid & 31] = sc[(tid >> 5)*DD + k0 + (tid & 31)];
  __syncthreads();
  f32x4 acc[4] = {};
  for (int kk = 0; kk < 32; ++kk){
    const float4 wv4 = *(const float4*)(w + (size_t)(k0 + kk)*6144 + col4);
    #pragma unroll
    for (int b = 0; b < 4; ++b){
      float s = sl[b][kk];
      acc[b][0] += s*wv4.x; acc[b][1] += s*wv4.y; acc[b][2] += s*wv4.z; acc[b][3] += s*wv4.w;
    }
  }
  #pragma unroll
  for (int b = 0; b < 4; ++b)
    #pragma unroll
    for (int j = 0; j < 4; ++j)
      atomicAdd(&mod[(size_t)b*6144 + col4 + j], acc[b][j]);
}

// ---------- RMSNorm (+optional adaLN scale/shift) ----------
__global__ __launch_bounds__(256) void k_rms(const float* __restrict__ X, const float* __restrict__ w,
                      const float* __restrict__ mod, int sc_off, int sh_off,
                      bf16* __restrict__ out, int use_mod){
  __shared__ float red[256];
  int row = blockIdx.x;
  int b = row >> 10;
  int tid = threadIdx.x;
  const float* xr = X + (size_t)row*DD;
  float s = 0.f;
  #pragma unroll
  for (int i = 0; i < 4; ++i){ float v = xr[tid + i*256]; s += v*v; }
  red[tid] = s; __syncthreads();
  for (int st = 128; st > 0; st >>= 1){ if (tid < st) red[tid] += red[tid+st]; __syncthreads(); }
  float rstd = rsqrtf(red[0]*(1.f/DD) + 1e-6f);
  bf16* orow = out + (size_t)row*DD;
  const float* mrow = use_mod ? (mod + (size_t)b*6*DD) : nullptr;
  #pragma unroll
  for (int i = 0; i < 4; ++i){
    int d = tid + i*256;
    float v = xr[d]*rstd*w[d];
    if (use_mod) v = v*(1.f + mrow[sc_off + d]) + mrow[sh_off + d];
    orow[d] = f2bf(v);
  }
}

// ---------- MFMA GEMM v2: C(MxN,bf16) = A(MxK,bf16) @ BT(NxK,bf16)^T [+bias][gelu] ----------
// 128x128 tile, BK=64, gl2lds staging, XOR-swizzled LDS (T2 + rule 21), XCD swizzle (T1).
__global__ __launch_bounds__(256,2) void k_mm2(const ushort* __restrict__ A, const ushort* __restrict__ BT,
                      const float* __restrict__ bias, ushort* __restrict__ C,
                      int M, int N, int K, int act){
  __shared__ ushort As[128*64];   // phys [row][kphys]; logical k-slot t at phys slot t^(row&7)
  __shared__ ushort Bs[128*64];
  int tid = threadIdx.x, lane = tid & 63, wv = tid >> 6;
  int l15 = lane & 15, quad = lane >> 4;
  int gx = gridDim.x;
  int nf = xcd_swz_flat(blockIdx.y*gx + blockIdx.x, gx*gridDim.y);
  int bm = (nf / gx)*128, bn = (nf % gx)*128;
  int wm = (wv & 1)*64, wn = (wv >> 1)*64;
  int lr = lane >> 3, lc = lane & 7;
  int ksw = (lc ^ lr) << 3;
  f32x4 acc[4][4] = {};
  const ushort* Abase = A  + (size_t)(bm + wv*32 + lr)*K + ksw;
  const ushort* Bbase = BT + (size_t)(bn + wv*32 + lr)*K + ksw;
  ushort* AsW = As + wv*2048;
  ushort* BsW = Bs + wv*2048;
  int swr = (l15 & 7) << 3;
  for (int k0 = 0; k0 < K; k0 += 64){
    #pragma unroll
    for (int i = 0; i < 4; ++i){
      gl2lds16(Abase + k0 + (size_t)(i*8)*K, AsW + i*512);
      gl2lds16(Bbase + k0 + (size_t)(i*8)*K, BsW + i*512);
    }
    __syncthreads();
    #pragma unroll
    for (int ks = 0; ks < 2; ++ks){
      bf16x8 af[4], bfr[4];
      #pragma unroll
      for (int mi = 0; mi < 4; ++mi){
        int r = wm + mi*16 + l15;
        af[mi] = __builtin_bit_cast(bf16x8, *(const uint4*)(As + r*64 + ((ks*32 + quad*8) ^ swr)));
      }
      #pragma unroll
      for (int nj = 0; nj < 4; ++nj){
        int r = wn + nj*16 + l15;
        bfr[nj] = __builtin_bit_cast(bf16x8, *(const uint4*)(Bs + r*64 + ((ks*32 + quad*8) ^ swr)));
      }
      #pragma unroll
      for (int mi = 0; mi < 4; ++mi)
        #pragma unroll
        for (int nj = 0; nj < 4; ++nj)
          acc[mi][nj] = __builtin_amdgcn_mfma_f32_16x16x32_bf16(af[mi], bfr[nj], acc[mi][nj], 0, 0, 0);
    }
    __syncthreads();
  }
  #pragma unroll
  for (int nj = 0; nj < 4; ++nj){
    int col = bn + wn + nj*16 + l15;
    float bv = bias ? bias[col] : 0.f;
    #pragma unroll
    for (int mi = 0; mi < 4; ++mi){
      #pragma unroll
      for (int r = 0; r < 4; ++r){
        int row = bm + wm + mi*16 + quad*4 + r;
        float v = acc[mi][nj][r] + bv;
        if (act) v = geluf_(v);
        C[(size_t)row*N + col] = fbits(v);
      }
    }
  }
}

// ---------- MFMA GEMM half-width: BM=128, BN=64 — for grid-starved GEMMs ----------
__global__ __launch_bounds__(256,2) void k_mm2h(const ushort* __restrict__ A, const ushort* __restrict__ BT,
                      const float* __restrict__ bias, ushort* __restrict__ C,
                      int M, int N, int K, int act){
  __shared__ ushort As[128*64];
  __shared__ ushort Bs[64*64];
  int tid = threadIdx.x, lane = tid & 63, wv = tid >> 6;
  int l15 = lane & 15, quad = lane >> 4;
  int gx = gridDim.x;
  int nf = xcd_swz_flat(blockIdx.y*gx + blockIdx.x, gx*gridDim.y);
  int bm = (nf / gx)*128, bn = (nf % gx)*64;
  int wm = wv*32;
  int lr = lane >> 3, lc = lane & 7;
  int ksw = (lc ^ lr) << 3;
  f32x4 acc[2][4] = {};
  const ushort* Abase = A  + (size_t)(bm + wv*32 + lr)*K + ksw;
  const ushort* Bbase = BT + (size_t)(bn + wv*16 + lr)*K + ksw;
  ushort* AsW = As + wv*2048;
  ushort* BsW = Bs + wv*1024;
  int swr = (l15 & 7) << 3;
  for (int k0 = 0; k0 < K; k0 += 64){
    #pragma unroll
    for (int i = 0; i < 4; ++i)
      gl2lds16(Abase + k0 + (size_t)(i*8)*K, AsW + i*512);
    #pragma unroll
    for (int i = 0; i < 2; ++i)
      gl2lds16(Bbase + k0 + (size_t)(i*8)*K, BsW + i*512);
    __syncthreads();
    #pragma unroll
    for (int ks = 0; ks < 2; ++ks){
      bf16x8 af[2], bfr[4];
      #pragma unroll
      for (int mi = 0; mi < 2; ++mi){
        int r = wm + mi*16 + l15;
        af[mi] = __builtin_bit_cast(bf16x8, *(const uint4*)(As + r*64 + ((ks*32 + quad*8) ^ swr)));
      }
      #pragma unroll
      for (int nj = 0; nj < 4; ++nj){
        int r = nj*16 + l15;
        bfr[nj] = __builtin_bit_cast(bf16x8, *(const uint4*)(Bs + r*64 + ((ks*32 + quad*8) ^ swr)));
      }
      #pragma unroll
      for (int mi = 0; mi < 2; ++mi)
        #pragma unroll
        for (int nj = 0; nj < 4; ++nj)
          acc[mi][nj] = __builtin_amdgcn_mfma_f32_16x16x32_bf16(af[mi], bfr[nj], acc[mi][nj], 0, 0, 0);
    }
    __syncthreads();
  }
  #pragma unroll
  for (int nj = 0; nj < 4; ++nj){
    int col = bn + nj*16 + l15;
    float bv = bias ? bias[col] : 0.f;
    #pragma unroll
    for (int mi = 0; mi < 2; ++mi){
      #pragma unroll
      for (int r = 0; r < 4; ++r){
        int row = bm + wm + mi*16 + quad*4 + r;
        float v = acc[mi][nj][r] + bv;
        if (act) v = geluf_(v);
        C[(size_t)row*N + col] = fbits(v);
      }
    }
  }
}

// ---------- RoPE: in (B,NN,NHp,64) -> out (B,NHp,NN,64), rotated ----------
__global__ void k_rope(const bf16* __restrict__ in, const float* __restrict__ cw,
                       const float* __restrict__ sw, bf16* __restrict__ out, int NHp, int n){
  int idx = blockIdx.x*256 + threadIdx.x;
  if (idx >= n) return;
  int d2 = idx & 31; int t = idx >> 5;
  int nn = t % NN; t /= NN; int h = t % NHp; int b = t / NHp;
  const bf16* base = in + ((size_t)((b*NN+nn)*NHp + h))*HDIM;
  float e = bf2f(base[2*d2]), o = bf2f(base[2*d2+1]);
  float c = cw[nn*32 + d2], s = sw[nn*32 + d2];
  bf16* ob = out + ((size_t)((b*NHp+h)*NN + nn))*HDIM;
  ob[d2]      = f2bf(e*c - o*s);
  ob[32 + d2] = f2bf(e*s + o*c);
}

// ---------- transpose (B,T,NHp,64) -> (B,NHp,T,64) ----------
__global__ void k_tr(const bf16* __restrict__ in, bf16* __restrict__ out, int T, int NHp, int n){
  int idx = blockIdx.x*256 + threadIdx.x;
  if (idx >= n) return;
  int d = idx & 63; int t = idx >> 6;
  int h = t % NHp; t /= NHp; int tok = t % T; int b = t / T;
  out[((size_t)((b*NHp+h)*T + tok))*64 + d] = in[idx];
}

// ---------- V transpose (B,T,NHp,64) -> (B,NHp,64,T) ----------
__global__ void k_trv(const bf16* __restrict__ in, bf16* __restrict__ out, int T, int NHp, int n){
  int idx = blockIdx.x*256 + threadIdx.x;
  if (idx >= n) return;
  int d = idx & 63; int t = idx >> 6;
  int h = t % NHp; t /= NHp; int tok = t % T; int b = t / T;
  out[((size_t)(b*NHp+h)*64 + d)*T + tok] = in[idx];
}

// ---------- MFMA flash attention (defer-max softmax, gl2lds staging, XCD swizzle) ----------
__global__ __launch_bounds__(256) void k_fattn(const ushort* __restrict__ Q, const ushort* __restrict__ K,
                      const ushort* __restrict__ V, ushort* __restrict__ O,
                      int NH, int NKV, int Nq, int Nk, float scale){
  __shared__ ushort Kt[64*64];
  __shared__ ushort Vt[64*64];
  __shared__ ushort Ps[4][16*72];  // per-wave [q][key], stride 72
  int tid = threadIdx.x, lane = tid & 63, wv = tid >> 6;
  int l15 = lane & 15, quad = lane >> 4;
  int lr = lane >> 3, lc = lane & 7;
  int ksw = (lc ^ lr) << 3;
  int swr = (l15 & 7) << 3;
  int nqt = Nq >> 6;
  int nf = xcd_swz_flat(blockIdx.x, gridDim.x);   // blocks of one head stay on one XCD
  int qt = nf % nqt; int t = nf / nqt; int h = t % NH; int b = t / NH;
  int kvh = h / (NH / NKV);
  const ushort* Kb = K + (size_t)(b*NKV+kvh)*Nk*64 + ksw;
  const ushort* Vb = V + (size_t)(b*NKV+kvh)*64*Nk + ksw;
  const ushort* Qp = Q + ((size_t)((b*NH+h)*Nq + qt*64 + wv*16 + l15))*64;
  // fold softmax scale AND log2(e) into Q (scores land in log2 domain)
  float qscale = scale * 1.44269504f;
  uint4 qraw0 = *(const uint4*)(Qp + quad*8);
  uint4 qraw1 = *(const uint4*)(Qp + 32 + quad*8);
  u16x8 q0 = __builtin_bit_cast(u16x8, qraw0), q1 = __builtin_bit_cast(u16x8, qraw1);
  #pragma unroll
  for (int j = 0; j < 8; ++j){ q0[j] = fbits(ubf(q0[j])*qscale); q1[j] = fbits(ubf(q1[j])*qscale); }
  bf16x8 qf0 = __builtin_bit_cast(bf16x8, q0);
  bf16x8 qf1 = __builtin_bit_cast(bf16x8, q1);
  f32x4 acc[4] = {};
  float m_run[4]  = {0.f,0.f,0.f,0.f};
  float l_part[4] = {0.f,0.f,0.f,0.f};
  ushort* Pw = Ps[wv];
  int wrow = wv*16;
  for (int t0 = 0; t0 < Nk; t0 += 64){
    #pragma unroll
    for (int i = 0; i < 2; ++i){
      int row = wrow + i*8 + lr;
      gl2lds16(Kb + (size_t)(t0+row)*64, Kt + (wrow + i*8)*64);
      gl2lds16(Vb + (size_t)row*Nk + t0, Vt + (wrow + i*8)*64);
    }
    __syncthreads();
    f32x4 s[4] = {};
    __builtin_amdgcn_s_setprio(1);
    #pragma unroll
    for (int nj = 0; nj < 4; ++nj){
      const ushort* kr = Kt + (nj*16+l15)*64;
      bf16x8 kf0 = __builtin_bit_cast(bf16x8, *(const uint4*)(kr + ((quad*8) ^ swr)));
      s[nj] = __builtin_amdgcn_mfma_f32_16x16x32_bf16(qf0, kf0, s[nj], 0, 0, 0);
      bf16x8 kf1 = __builtin_bit_cast(bf16x8, *(const uint4*)(kr + ((32 + quad*8) ^ swr)));
      s[nj] = __builtin_amdgcn_mfma_f32_16x16x32_bf16(qf1, kf1, s[nj], 0, 0, 0);
    }
    __builtin_amdgcn_s_setprio(0);
    float tl[4];
    #pragma unroll
    for (int r = 0; r < 4; ++r)
      tl[r] = fmaxf(fmaxf(s[0][r], s[1][r]), fmaxf(s[2][r], s[3][r]));
    float dmax = fmaxf(fmaxf(tl[0]-m_run[0], tl[1]-m_run[1]),
                       fmaxf(tl[2]-m_run[2], tl[3]-m_run[3]));
    if (__any(dmax > 8.f)){
      #pragma unroll
      for (int r = 0; r < 4; ++r){
        float tm = tl[r];
        #pragma unroll
        for (int off = 8; off; off >>= 1) tm = fmaxf(tm, __shfl_xor(tm, off, 64));
        float mn = fmaxf(m_run[r], tm);
        float al = exp2f(m_run[r] - mn);
        m_run[r] = mn;
        l_part[r] *= al;
        #pragma unroll
        for (int nj = 0; nj < 4; ++nj) acc[nj][r] *= al;
      }
    }
    #pragma unroll
    for (int nj = 0; nj < 4; ++nj)
      #pragma unroll
      for (int r = 0; r < 4; ++r){
        float p = exp2f(s[nj][r] - m_run[r]);
        s[nj][r] = p;
        Pw[(quad*4+r)*72 + nj*16 + l15] = fbits(p);
      }
    #pragma unroll
    for (int r = 0; r < 4; ++r)
      l_part[r] += (s[0][r]+s[1][r]) + (s[2][r]+s[3][r]);
    bf16x8 pf0 = __builtin_bit_cast(bf16x8, *(const uint4*)(Pw + l15*72 + quad*8));
    bf16x8 pf1 = __builtin_bit_cast(bf16x8, *(const uint4*)(Pw + l15*72 + 32 + quad*8));
    __builtin_amdgcn_s_setprio(1);
    #pragma unroll
    for (int nj = 0; nj < 4; ++nj){
      const ushort* vr = Vt + (nj*16+l15)*64;
      bf16x8 vf0 = __builtin_bit_cast(bf16x8, *(const uint4*)(vr + ((quad*8) ^ swr)));
      acc[nj] = __builtin_amdgcn_mfma_f32_16x16x32_bf16(pf0, vf0, acc[nj], 0, 0, 0);
      bf16x8 vf1 = __builtin_bit_cast(bf16x8, *(const uint4*)(vr + ((32 + quad*8) ^ swr)));
      acc[nj] = __builtin_amdgcn_mfma_f32_16x16x32_bf16(pf1, vf1, acc[nj], 0, 0, 0);
    }
    __builtin_amdgcn_s_setprio(0);
    __syncthreads();
  }
  float inv[4];
  #pragma unroll
  for (int r = 0; r < 4; ++r){
    float ls = l_part[r];
    #pragma unroll
    for (int off = 8; off; off >>= 1) ls += __shfl_xor(ls, off, 64);
    inv[r] = 1.f / ls;
  }
  int nbase = qt*64 + wv*16 + quad*4;
  #pragma unroll
  for (int r = 0; r < 4; ++r){
    size_t ob = ((size_t)((b*Nq + nbase + r)*NH + h))*64;
    #pragma unroll
    for (int nj = 0; nj < 4; ++nj)
      O[ob + nj*16 + l15] = fbits(acc[nj][r]*inv[r]);
  }
}

// ---------- residual: X = (base? base : X) + (mod? g : 1) * val ----------
__global__ void k_resid(float* __restrict__ X, const float* __restrict__ base,
                        const bf16* __restrict__ val,
                        const float* __restrict__ mod, int goff, int n){
  int i = blockIdx.x*256 + threadIdx.x;
  if (i >= n) return;
  float g = 1.f;
  if (mod){ int b = i >> 20; int d = i & 1023; g = mod[b*6144 + goff + d]; }
  float x0 = base ? base[i] : X[i];
  X[i] = x0 + g*bf2f(val[i]);
}

// ---------- concat [X(fp32), VST(bf16)] -> CAT bf16 ----------
__global__ void k_concat(const float* __restrict__ X, const bf16* __restrict__ V,
                         bf16* __restrict__ C, int n){
  int i = blockIdx.x*256 + threadIdx.x;
  if (i >= n) return;
  int row = i >> 11, col = i & 2047;
  C[i] = (col < 1024) ? f2bf(X[(size_t)row*1024 + col]) : V[(size_t)row*1024 + col - 1024];
}

// ---------- integrator control update ----------
__global__ void k_ctrl(const bf16* __restrict__ ctrl, const float* __restrict__ X,
                       bf16* __restrict__ VST, bf16* __restrict__ XN,
                       const float* __restrict__ mu, int n){
  int i = blockIdx.x*256 + threadIdx.x;
  if (i >= n) return;
  int row = i >> 10, d = i & 1023;
  const bf16* cr = ctrl + (size_t)row*3072;
  float alpha = sigmf_(bf2f(cr[d]));
  float braw  = bf2f(cr[1024 + d]);
  float beta  = fmaxf(braw, 0.f) + log1pf(expf(-fabsf(braw)));
  float gate  = sigmf_(bf2f(cr[2048 + d]));
  float vn = alpha*bf2f(VST[i]) - beta*(X[i] - mu[d]);
  VST[i] = f2bf(vn);
  XN[i]  = f2bf(X[i] + 0.1f*gate*vn);
}

// ---------- hg2: hp = sigmoid(hg1out @ w + b) ; fp32 halt tail ----------
__global__ __launch_bounds__(64) void k_hg2(const bf16* __restrict__ hin, const float* __restrict__ w,
                     const float* __restrict__ bb, float* __restrict__ hp,
                     float* __restrict__ oout, int it){
  int r = blockIdx.x; int lane = threadIdx.x;
  const bf16* hr = hin + (size_t)r*256;
  float s = 0.f;
  #pragma unroll
  for (int i = 0; i < 4; ++i) s += bf2f(hr[lane + i*64])*w[lane + i*64];
  for (int off = 32; off; off >>= 1) s += __shfl_xor(s, off, 64);
  if (lane == 0){
    float v = sigmf_(s + bb[0]);
    hp[r] = v;
    int b = r >> 10, nn = r & 1023;
    oout[((size_t)(b*2 + it) << 10) + nn] = v;
  }
}

// ---------- integ += hp * refined * int_w ----------
__global__ void k_integ(float* __restrict__ X, const float* __restrict__ hp,
                        const bf16* __restrict__ rf, const float* __restrict__ iw, int n){
  int i = blockIdx.x*256 + threadIdx.x;
  if (i >= n) return;
  int row = i >> 10, d = i & 1023;
  X[i] += hp[row]*bf2f(rf[i])*iw[d];
}

extern "C" void kernel_launch(void* const* d_in, const int* in_sizes, int n_in,
                              void* d_out, int out_size, void* d_ws, size_t ws_size,
                              hipStream_t stream) {
  const float* x_in  = (const float*)d_in[0];
  const float* c_in  = (const float*)d_in[1];
  const float* ctx_in= (const float*)d_in[2];
  const float* cosw  = (const float*)d_in[3];
  const float* sinw  = (const float*)d_in[4];
  const float* wq    = (const float*)d_in[5];
  const float* wk    = (const float*)d_in[6];
  const float* wv    = (const float*)d_in[7];
  const float* wo    = (const float*)d_in[8];
  const float* cwq   = (const float*)d_in[9];
  const float* cwk   = (const float*)d_in[10];
  const float* cwv   = (const float*)d_in[11];
  const float* cwo   = (const float*)d_in[12];
  const float* fc1_w = (const float*)d_in[13];
  const float* fc1_b = (const float*)d_in[14];
  const float* fc2_w = (const float*)d_in[15];
  const float* fc2_b = (const float*)d_in[16];
  const float* ada_w = (const float*)d_in[17];
  const float* ada_b = (const float*)d_in[18];
  const float* n1    = (const float*)d_in[19];
  const float* n2    = (const float*)d_in[20];
  const float* n3    = (const float*)d_in[21];
  const float* int_w = (const float*)d_in[22];
  const float* mu    = (const float*)d_in[23];
  const float* hg1_w = (const float*)d_in[24];
  const float* hg1_b = (const float*)d_in[25];
  const float* hg2_w = (const float*)d_in[26];
  const float* hg2_b = (const float*)d_in[27];
  const float* ct1_w = (const float*)d_in[28];
  const float* ct1_b = (const float*)d_in[29];
  const float* ct2_w = (const float*)d_in[30];
  const float* ct2_b = (const float*)d_in[31];
  const float* rf1_w = (const float*)d_in[32];
  const float* rf1_b = (const float*)d_in[33];
  const float* rf2_w = (const float*)d_in[34];
  const float* rf2_b = (const float*)d_in[35];

  float* out_f  = (float*)d_out;
  float* out_hp = out_f + (size_t)BB*NN*DD;

  // ---- workspace map (~112 MB) ----
  char* wsb = (char*)d_ws;
  const size_t Mi = 1u << 20;
  float* X  = (float*)wsb;                    // [0,16MB)
  bf16*  Hh = (bf16*)(wsb + 16*Mi);           // [16,24MB)
  bf16*  Qb = (bf16*)(wsb + 24*Mi);           // [24,32MB)
  bf16*  R  = (bf16*)(wsb + 32*Mi);           // [32,64MB)
  bf16*  QR  = R;
  bf16*  SAb = R + 4*Mi;
  bf16*  KP  = R + 8*Mi;
  bf16*  VP  = R + 9*Mi;
  bf16*  KR  = R + 10*Mi;
  bf16*  VR  = R + 11*Mi;
  bf16*  CTXB= R + 12*Mi;
  bf16*  BIG = R;
  bf16*  CT1 = R + 12*Mi;
  bf16*  HG1 = R + 12*Mi;
  bf16*  RFO = R + 8*Mi;
  float* SIL = (float*)(wsb + 64*Mi);
  float* MOD = SIL + 4096;
  float* HP  = MOD + 24576;
  bf16*  VST = Qb;
  bf16*  XN  = Hh;
  // transposed bf16 weights [N][K] at +65MB (46.5MB)
  bf16* WT   = (bf16*)(wsb + 65*Mi);
  bf16* wqT  = WT;                 // 1024x1024
  bf16* wkT  = wqT  + 1048576;     // 256x1024
  bf16* wvT  = wkT  + 262144;      // 256x1024
  bf16* woT  = wvT  + 262144;      // 1024x1024
  bf16* cwqT = woT  + 1048576;     // 1024x1024
  bf16* cwkT = cwqT + 1048576;     // 1024x2048
  bf16* cwvT = cwkT + 2097152;     // 1024x2048
  bf16* cwoT = cwvT + 2097152;     // 1024x1024
  bf16* fc1T = cwoT + 1048576;     // 4096x1024
  bf16* fc2T = fc1T + 4194304;     // 1024x4096
  bf16* ct1T = fc2T + 4194304;     // 512x2048
  bf16* ct2T = ct1T + 1048576;     // 3072x512
  bf16* rf1T = ct2T + 1572864;     // 2048x1024
  bf16* rf2T = rf1T + 2097152;     // 1024x2048
  bf16* hg1T = rf2T + 2097152;     // 256x1024

  const int NT = BB*NN*DD;
  const float scale = 0.125f;
  #define G1(n) dim3(((n)+255)/256), dim3(256)
  #define WTR(src,dst,K,N) k_wt<<<dim3((N)/64,(K)/64), dim3(256), 0, stream>>>((src),(dst),(K),(N))
  #define MM(Aptr,BTptr,biasptr,Cptr,M,N,K,act) \
    k_mm2<<<dim3((N)/128,(M)/128), dim3(256), 0, stream>>>((const ushort*)(Aptr),(const ushort*)(BTptr),(biasptr),(ushort*)(Cptr),(M),(N),(K),(act))
  #define MMH(Aptr,BTptr,biasptr,Cptr,M,N,K,act) \
    k_mm2h<<<dim3((N)/64,(M)/128), dim3(256), 0, stream>>>((const ushort*)(Aptr),(const ushort*)(BTptr),(biasptr),(ushort*)(Cptr),(M),(N),(K),(act))

  // ---- weight prep: fp32 [K][N] -> bf16 [N][K] ----
  WTR(wq,   wqT, 1024, 1024);
  WTR(wk,   wkT, 1024, 256);
  WTR(wv,   wvT, 1024, 256);
  WTR(wo,   woT, 1024, 1024);
  WTR(cwq,  cwqT,1024, 1024);
  WTR(cwk,  cwkT,2048, 1024);
  WTR(cwv,  cwvT,2048, 1024);
  WTR(cwo,  cwoT,1024, 1024);
  WTR(fc1_w,fc1T,1024, 4096);
  WTR(fc2_w,fc2T,4096, 1024);
  WTR(ct1_w,ct1T,2048, 512);
  WTR(ct2_w,ct2T,512,  3072);
  WTR(rf1_w,rf1T,1024, 2048);
  WTR(rf2_w,rf2T,2048, 1024);
  WTR(hg1_w,hg1T,1024, 256);

  // mod = silu(c) @ ada_w + ada_b (K-split atomic GEMV). No x copy: first RMS reads x_in.
  k_silu<<<G1(BB*DD), 0, stream>>>(c_in, SIL, BB*DD);
  k_adab<<<G1(BB*6144), 0, stream>>>(ada_b, MOD, BB*6144);
  k_ada2<<<dim3(6,32), dim3(256), 0, stream>>>(SIL, ada_w, MOD);

  // ---- self-attention ----
  k_rms<<<dim3(4096), dim3(256), 0, stream>>>(x_in, n1, MOD, DD, 0, Hh, 1);
  MM(Hh, wqT, nullptr, Qb, 4096, 1024, 1024, 0);
  MMH(Hh, wkT, nullptr, KP, 4096, 256, 1024, 0);
  MMH(Hh, wvT, nullptr, VP, 4096, 256, 1024, 0);
  k_rope<<<G1(BB*HH*NN*32), 0, stream>>>(Qb, cosw, sinw, QR, HH, BB*HH*NN*32);
  k_rope<<<G1(BB*KVH*NN*32), 0, stream>>>(KP, cosw, sinw, KR, KVH, BB*KVH*NN*32);
  k_trv<<<G1(BB*NN*KVH*64), 0, stream>>>(VP, VR, NN, KVH, BB*NN*KVH*64);
  k_fattn<<<dim3(BB*HH*(NN/64)), dim3(256), 0, stream>>>((const ushort*)QR, (const ushort*)KR,
      (const ushort*)VR, (ushort*)SAb, HH, KVH, NN, NN, scale);
  MM(SAb, woT, nullptr, Hh, 4096, 1024, 1024, 0);
  k_resid<<<G1(NT), 0, stream>>>(X, x_in, Hh, MOD, 2*DD, NT);

  // ---- cross-attention ----
  k_rms<<<dim3(4096), dim3(256), 0, stream>>>(X, n2, nullptr, 0, 0, Hh, 0);
  MM(Hh, cwqT, nullptr, Qb, 4096, 1024, 1024, 0);
  k_tr<<<G1(NT), 0, stream>>>(Qb, QR, NN, HH, NT);
  k_f2bfv<<<G1(BB*SS*CTXD), 0, stream>>>(ctx_in, CTXB, BB*SS*CTXD);
  MMH(CTXB, cwkT, nullptr, KP, 512, 1024, 2048, 0);
  MMH(CTXB, cwvT, nullptr, VP, 512, 1024, 2048, 0);
  k_tr<<<G1(BB*SS*HH*64), 0, stream>>>(KP, KR, SS, HH, BB*SS*HH*64);
  k_trv<<<G1(BB*SS*HH*64), 0, stream>>>(VP, VR, SS, HH, BB*SS*HH*64);
  k_fattn<<<dim3(BB*HH*(NN/64)), dim3(256), 0, stream>>>((const ushort*)QR, (const ushort*)KR,
      (const ushort*)VR, (ushort*)SAb, HH, HH, NN, SS, scale);
  MM(SAb, cwoT, nullptr, Hh, 4096, 1024, 1024, 0);
  k_resid<<<G1(NT), 0, stream>>>(X, nullptr, Hh, nullptr, 0, NT);

  // ---- MLP ----
  k_rms<<<dim3(4096), dim3(256), 0, stream>>>(X, n3, MOD, 4*DD, 3*DD, Hh, 1);
  MM(Hh, fc1T, fc1_b, BIG, 4096, 4096, 1024, 1);
  MMH(BIG, fc2T, fc2_b, Qb, 4096, 1024, 4096, 0);
  k_resid<<<G1(NT), 0, stream>>>(X, nullptr, Qb, MOD, 5*DD, NT);

  // ---- integrator (NITER=2) ----
  k_zero16<<<G1(NT), 0, stream>>>((unsigned short*)VST, NT);
  for (int it = 0; it < 2; ++it){
    k_concat<<<G1(2*NT), 0, stream>>>(X, VST, BIG, 2*NT);
    MMH(BIG, ct1T, ct1_b, CT1, 4096, 512, 2048, 1);
    MM(CT1, ct2T, ct2_b, BIG, 4096, 3072, 512, 0);
    k_ctrl<<<G1(NT), 0, stream>>>(BIG, X, VST, XN, mu, NT);
    MMH(XN, hg1T, hg1_b, HG1, 4096, 256, 1024, 1);
    k_hg2<<<dim3(4096), dim3(64), 0, stream>>>(HG1, hg2_w, hg2_b, HP, out_hp, it);
    MM(XN, rf1T, rf1_b, BIG, 4096, 2048, 1024, 1);
    MMH(BIG, rf2T, rf2_b, RFO, 4096, 1024, 2048, 0);
    k_integ<<<G1(NT), 0, stream>>>(X, HP, RFO, int_w, NT);
  }
  // ---- final output: FP32 ----
  k_copy4<<<G1(NT/4), 0, stream>>>((const float4*)X, (float4*)out_f, NT/4);
  #undef G1
  #undef WTR
  #undef MM
  #undef MMH
}